// Round 8
// baseline (386.300 us; speedup 1.0000x reference)
//
#include <hip/hip_runtime.h>
#include <hip/hip_bf16.h>
#include <math.h>

#define HF 128
#define NL 128
#define NP 1024
#define NB 4
#define EPSF 1e-8f
#define NITEMS 2048   // (b*128+i) x j-quarter(256)

typedef short bf16x8 __attribute__((ext_vector_type(8)));
typedef float f32x4 __attribute__((ext_vector_type(4)));

__device__ __forceinline__ float fast_rcp(float x){ return __builtin_amdgcn_rcpf(x); }
__device__ __forceinline__ float silu_f(float x){ return x*fast_rcp(1.f+__expf(-x)); }
__device__ __forceinline__ float sigmoid_f(float x){ return fast_rcp(1.f+__expf(-x)); }
__device__ __forceinline__ float tanh_f(float x){ return 1.f - 2.f*fast_rcp(1.f+__expf(2.f*x)); }
__device__ __forceinline__ unsigned short f2bf(float f){ __hip_bfloat16 h=__float2bfloat16(f); return *(unsigned short*)&h; }
__device__ __forceinline__ float bf2f(short u){ unsigned int x = ((unsigned int)(unsigned short)u)<<16; float r; __builtin_memcpy(&r,&x,4); return r; }

// ---------------------------------------------------------------------------
// Precompute: Al/Cl (f32, ligand), Ap/Vp/Cp (bf16, protein, 4 rows/block for
// latency hiding), WaT/WvT transposes, and zeroes the work-queue counter.
// ---------------------------------------------------------------------------
__global__ __launch_bounds__(128) void precompute_kernel(
    const float* __restrict__ h_ligand, const float* __restrict__ h_protein,
    const float* __restrict__ aW1, const float* __restrict__ ab1,
    const float* __restrict__ vW1, const float* __restrict__ vb1,
    const float* __restrict__ cW1, const float* __restrict__ cb1,
    const float* __restrict__ aW2, const float* __restrict__ vW2,
    float* __restrict__ Al, float* __restrict__ Cl,
    unsigned short* __restrict__ Ap, unsigned short* __restrict__ Vp,
    unsigned short* __restrict__ Cp,
    unsigned short* __restrict__ WaT, unsigned short* __restrict__ WvT,
    int* __restrict__ counter)
{
    const int blk = blockIdx.x, n = threadIdx.x;
    if (blk < 64) {
        __shared__ float rows[8][HF];
        const int r0 = blk*8;
        for (int idx=n; idx<8*HF; idx+=128) rows[idx>>7][idx&127] = h_ligand[r0*HF+idx];
        __syncthreads();
        float aA[8], aC[8];
        const float bA = ab1[n], bC = cb1[n];
        #pragma unroll
        for (int r=0;r<8;++r){ aA[r]=bA; aC[r]=bC; }
        #pragma unroll 4
        for (int k=0;k<HF;++k){
            float wA = aW1[k*HF+n], wC = cW1[k*HF+n];
            #pragma unroll
            for (int r=0;r<8;++r){ aA[r]=fmaf(rows[r][k],wA,aA[r]); aC[r]=fmaf(rows[r][k],wC,aC[r]); }
        }
        #pragma unroll
        for (int r=0;r<8;++r){ Al[(r0+r)*HF+n]=aA[r]; Cl[(r0+r)*HF+n]=aC[r]; }
    } else if (blk < 1088) {
        __shared__ float rows[4][HF];
        const int r0 = (blk-64)*4;
        for (int idx=n; idx<4*HF; idx+=128) rows[idx>>7][idx&127] = h_protein[r0*HF+idx];
        __syncthreads();
        float aA[4], aV[4], aC[4];
        const float bV = vb1[n];
        #pragma unroll
        for (int r=0;r<4;++r){ aA[r]=0.f; aV[r]=bV; aC[r]=0.f; }
        #pragma unroll 2
        for (int k=0;k<HF;++k){
            float wA = aW1[(HF+k)*HF+n], wV = vW1[k*HF+n], wC = cW1[(HF+k)*HF+n];
            #pragma unroll
            for (int r=0;r<4;++r){
                float h = rows[r][k];
                aA[r]=fmaf(h,wA,aA[r]); aV[r]=fmaf(h,wV,aV[r]); aC[r]=fmaf(h,wC,aC[r]);
            }
        }
        #pragma unroll
        for (int r=0;r<4;++r){
            Ap[(r0+r)*HF+n]=f2bf(aA[r]); Vp[(r0+r)*HF+n]=f2bf(aV[r]); Cp[(r0+r)*HF+n]=f2bf(aC[r]);
        }
    } else {
        const int m = blk - 1088;        // 0..15
        if (m == 0 && n == 0) *counter = 0;
        const float* W = (m<8) ? aW2 : vW2;
        unsigned short* WT = (m<8) ? WaT : WvT;
        const int n0 = (m&7)*16;
        #pragma unroll
        for (int kb=0; kb<16; ++kb) {
            int k = kb*8 + (n>>4);
            int col = n0 + (n&15);
            WT[col*HF + k] = f2bf(W[k*HF + col]);
        }
    }
}

// ---------------------------------------------------------------------------
// Main kernel: 1024 persistent blocks x 256 threads (4 waves, 2wj x 2wn).
// Work queue of 2048 items = (ii, j-quarter of 256).  Per block one-time:
// weight B-frags (wa/wv) loaded directly from global WaT/WvT into regs.
// Per item: geometry+compaction for 256 j, then r7's 3-barrier tile loop
// (32 compacted rows/tile) with LDS A/V tiles and AGPR-resident weights.
// LDS ~27 KB -> 4 blocks/CU; queue balances the variable-nact items.
// ---------------------------------------------------------------------------
__global__ __launch_bounds__(256,3) void egnn_main_kernel(
    const float* __restrict__ x_ligand, const float* __restrict__ x_protein,
    const float* __restrict__ ligand_mask, const float* __restrict__ protein_mask,
    const float* __restrict__ aW1, const float* __restrict__ ab2,
    const float* __restrict__ aW3, const float* __restrict__ ab3,
    const float* __restrict__ vW1, const float* __restrict__ vb2,
    const float* __restrict__ cW1, const float* __restrict__ cW2, const float* __restrict__ cb2,
    const float* __restrict__ Al, const float* __restrict__ Cl,
    const unsigned short* __restrict__ Ap, const unsigned short* __restrict__ Vp,
    const unsigned short* __restrict__ Cp,
    const unsigned short* __restrict__ WaT, const unsigned short* __restrict__ WvT,
    int* __restrict__ counter,
    float* __restrict__ out)
{
    __shared__ __align__(16) char tiles[16384];      // A [0,8K), V [8K,16K)
    __shared__ float ds_all[256], pme[256], dirx[256], diry[256], dirz[256];
    __shared__ unsigned short jlist[256];
    __shared__ float Al_s[HF], Cl_s[HF];
    __shared__ float aw1l[HF], cw1l[HF], vw1l[HF], cW2s[HF];
    __shared__ float attn_part[64], attn_e[32];
    __shared__ float hred[256];
    __shared__ float xw[12];
    __shared__ int nact_s, cur_s;

    const int t = threadIdx.x, lane = t&63, w = t>>6;
    const int wj = w>>1, wn = w&1;
    const int lr = lane&15, lg = lane>>4;

    // ---- block prologue (once): ii-independent consts + weight frags ----
    if (t < HF) {
        aw1l[t] = aW1[256*HF+t];
        cw1l[t] = cW1[256*HF+t];
        vw1l[t] = vW1[128*HF+t];
        cW2s[t] = cW2[t];
    }
    float ab2v[4], aw3v[4], vb2v[4];
    #pragma unroll
    for (int nt=0; nt<4; ++nt) {
        int n = wn*64 + nt*16 + lr;
        ab2v[nt] = ab2[n]; aw3v[nt] = aW3[n]; vb2v[nt] = vb2[n];
    }
    const float ab3v = ab3[0], cb2v = cb2[0];
    bf16x8 wa[4][4], wv[4][4];
    #pragma unroll
    for (int nt=0; nt<4; ++nt) {
        const int ncol = wn*64 + nt*16 + lr;
        #pragma unroll
        for (int ks=0; ks<4; ++ks) {
            wa[nt][ks] = *(const bf16x8*)(WaT + (size_t)ncol*HF + lg*8 + ks*32);
            wv[nt][ks] = *(const bf16x8*)(WvT + (size_t)ncol*HF + lg*8 + ks*32);
        }
    }

    const int brow = t >> 4, bcol = (t & 15)*8;   // tile build mapping
    const int crow = t >> 3, cg = t & 7;          // c-branch mapping

    // ---- work-queue loop ----
    for (;;) {
        __syncthreads();                 // prev item fully done; LDS reusable
        if (t == 0) cur_s = atomicAdd(counter, 1);
        __syncthreads();
        const int item = cur_s;
        if (item >= NITEMS) break;
        const int ii = item >> 2;        // b*128 + i
        const int q  = item & 3;
        const int b  = ii >> 7;
        const int jbase = q*256;

        // per-item consts + geometry (256 j)
        if (t < HF) {
            Al_s[t] = Al[(size_t)ii*HF+t];
            Cl_s[t] = Cl[(size_t)ii*HF+t];
        }
        const float xl0 = x_ligand[ii*3+0], xl1 = x_ligand[ii*3+1], xl2 = x_ligand[ii*3+2];
        const float* xp = x_protein + ((size_t)b*NP + jbase)*3;
        const float* pm = protein_mask + (size_t)b*NP + jbase;
        {
            const int jj = t;
            float r0 = xl0-xp[jj*3+0], r1 = xl1-xp[jj*3+1], r2 = xl2-xp[jj*3+2];
            float ds = r0*r0+r1*r1+r2*r2;
            float dist = sqrtf(ds+EPSF);
            float inv = fast_rcp(dist+EPSF);
            float e = dist < 10.f ? 1.f : 0.f;
            ds_all[jj]=ds; pme[jj]=pm[jj]*e;
            dirx[jj]=r0*inv; diry[jj]=r1*inv; dirz[jj]=r2*inv;
        }
        __syncthreads();
        if (w == 0) {
            int base = 0;
            #pragma unroll
            for (int c=0; c<4; ++c) {
                int jj = c*64 + lane;
                bool act = pme[jj] > 0.f;
                unsigned long long m = __ballot(act);
                int pos = base + __popcll(m & ((1ull<<lane)-1ull));
                if (act) jlist[pos] = (unsigned short)jj;
                base += __popcll(m);
            }
            if (lane == 0) nact_s = base;
        }
        __syncthreads();
        const int nact = nact_s;
        if (nact == 0) continue;
        const int ntiles = (nact + 31) >> 5;

        const unsigned short* Ap_b = Ap + ((size_t)b*NP + jbase)*HF;
        const unsigned short* Vp_b = Vp + ((size_t)b*NP + jbase)*HF;
        const unsigned short* Cp_b = Cp + ((size_t)b*NP + jbase)*HF;

        float hacc[4] = {0.f,0.f,0.f,0.f};
        float sae = 0.f;
        float xa0 = 0.f, xa1 = 0.f, xa2 = 0.f;

        for (int tile = 0; tile < ntiles; ++tile) {
            const int j0 = tile*32;

            // phase 1: build A tile (compacted rows)
            #pragma unroll
            for (int m = 0; m < 2; ++m) {
                const int row = m*16 + brow;
                const int grow = j0 + row;
                const int jl = jlist[grow < nact ? grow : 0];
                const float dsv = ds_all[jl];
                bf16x8 ap = *(const bf16x8*)(Ap_b + (size_t)jl*HF + bcol);
                f32x4 al0 = *(const f32x4*)&Al_s[bcol];
                f32x4 al1 = *(const f32x4*)&Al_s[bcol+4];
                f32x4 w0  = *(const f32x4*)&aw1l[bcol];
                f32x4 w1  = *(const f32x4*)&aw1l[bcol+4];
                bf16x8 pk;
                #pragma unroll
                for (int qq = 0; qq < 4; ++qq) {
                    pk[qq]   = (short)f2bf(silu_f(al0[qq] + bf2f(ap[qq])   + dsv*w0[qq]));
                    pk[qq+4] = (short)f2bf(silu_f(al1[qq] + bf2f(ap[qq+4]) + dsv*w1[qq]));
                }
                *(bf16x8*)(tiles + row*256 + ((bcol*2) ^ ((row & 7) << 4))) = pk;
            }
            __syncthreads();   // bar 1: A ready

            // phase 2: a-GEMM + attn partials; c-branch overlaps
            bf16x8 af[4];
            {
                int arow = wj*16 + lr;
                int rb = arow*256, sw = (arow & 7) << 4;
                #pragma unroll
                for (int ks = 0; ks < 4; ++ks)
                    af[ks] = *(bf16x8*)(tiles + rb + ((lg*16 + ks*64) ^ sw));
            }
            f32x4 acc[4];
            #pragma unroll
            for (int nt = 0; nt < 4; ++nt) {
                acc[nt] = (f32x4){0.f,0.f,0.f,0.f};
                #pragma unroll
                for (int ks = 0; ks < 4; ++ks)
                    acc[nt] = __builtin_amdgcn_mfma_f32_16x16x32_bf16(af[ks], wa[nt][ks], acc[nt], 0,0,0);
            }
            // c-branch (VALU)
            {
                const int growc = j0 + crow;
                const bool okc = growc < nact;
                const int jlc = jlist[okc ? growc : 0];
                const float pmec = okc ? pme[jlc] : 0.f;
                const float dsc = ds_all[jlc];
                float part = 0.f;
                const unsigned short* cp = Cp_b + (size_t)jlc*HF + cg*16;
                #pragma unroll
                for (int u = 0; u < 2; ++u) {
                    const int ch = cg*16 + u*8;
                    bf16x8 cv = *(const bf16x8*)(cp + u*8);
                    f32x4 cl0 = *(const f32x4*)&Cl_s[ch];
                    f32x4 cl1 = *(const f32x4*)&Cl_s[ch+4];
                    f32x4 w0  = *(const f32x4*)&cw1l[ch];
                    f32x4 w1  = *(const f32x4*)&cw1l[ch+4];
                    f32x4 s0  = *(const f32x4*)&cW2s[ch];
                    f32x4 s1  = *(const f32x4*)&cW2s[ch+4];
                    #pragma unroll
                    for (int qq = 0; qq < 4; ++qq) {
                        part += silu_f(cl0[qq] + bf2f(cv[qq])   + dsc*w0[qq]) * s0[qq];
                        part += silu_f(cl1[qq] + bf2f(cv[qq+4]) + dsc*w1[qq]) * s1[qq];
                    }
                }
                part += __shfl_xor(part,1); part += __shfl_xor(part,2); part += __shfl_xor(part,4);
                if (cg == 0) {
                    float cw = tanh_f(part + cb2v) * pmec;
                    xa0 = fmaf(dirx[jlc], cw, xa0);
                    xa1 = fmaf(diry[jlc], cw, xa1);
                    xa2 = fmaf(dirz[jlc], cw, xa2);
                }
            }
            // attn epilogue partials
            #pragma unroll
            for (int r = 0; r < 4; ++r) {
                float p = 0.f;
                #pragma unroll
                for (int nt = 0; nt < 4; ++nt)
                    p += silu_f(acc[nt][r] + ab2v[nt]) * aw3v[nt];
                p += __shfl_xor(p,1); p += __shfl_xor(p,2);
                p += __shfl_xor(p,4); p += __shfl_xor(p,8);
                if (lr == 0) attn_part[wn*32 + wj*16 + lg*4 + r] = p;
            }
            __syncthreads();   // bar 2: attn_part ready

            // phase 3: attn_e (t<32) + build V tile
            if (t < 32) {
                const int grow = j0 + t;
                const bool ok = grow < nact;
                const int j = jlist[ok ? grow : 0];
                attn_e[t] = sigmoid_f(attn_part[t] + attn_part[32+t] + ab3v) * (ok ? pme[j] : 0.f);
            }
            #pragma unroll
            for (int m = 0; m < 2; ++m) {
                const int row = m*16 + brow;
                const int grow = j0 + row;
                const int jl = jlist[grow < nact ? grow : 0];
                const float dsv = ds_all[jl];
                bf16x8 vp = *(const bf16x8*)(Vp_b + (size_t)jl*HF + bcol);
                f32x4 w0 = *(const f32x4*)&vw1l[bcol];
                f32x4 w1 = *(const f32x4*)&vw1l[bcol+4];
                bf16x8 pk;
                #pragma unroll
                for (int qq = 0; qq < 4; ++qq) {
                    pk[qq]   = (short)f2bf(silu_f(bf2f(vp[qq])   + dsv*w0[qq]));
                    pk[qq+4] = (short)f2bf(silu_f(bf2f(vp[qq+4]) + dsv*w1[qq]));
                }
                *(bf16x8*)(tiles + 8192 + row*256 + ((bcol*2) ^ ((row & 7) << 4))) = pk;
            }
            __syncthreads();   // bar 3: V + attn_e ready

            // phase 4: v-GEMM + h accumulate
            bf16x8 vf[4];
            {
                int arow = wj*16 + lr;
                int rb = 8192 + arow*256, sw = (arow & 7) << 4;
                #pragma unroll
                for (int ks = 0; ks < 4; ++ks)
                    vf[ks] = *(bf16x8*)(tiles + rb + ((lg*16 + ks*64) ^ sw));
            }
            float ae[4];
            #pragma unroll
            for (int r = 0; r < 4; ++r) { ae[r] = attn_e[wj*16 + lg*4 + r]; sae += ae[r]; }
            #pragma unroll
            for (int nt = 0; nt < 4; ++nt) {
                f32x4 a = (f32x4){0.f,0.f,0.f,0.f};
                #pragma unroll
                for (int ks = 0; ks < 4; ++ks)
                    a = __builtin_amdgcn_mfma_f32_16x16x32_bf16(vf[ks], wv[nt][ks], a, 0,0,0);
                hacc[nt] += ae[0]*a[0] + ae[1]*a[1] + ae[2]*a[2] + ae[3]*a[3];
            }
        }

        // ---- per-item reductions + atomics ----
        #pragma unroll
        for (int nt = 0; nt < 4; ++nt) {
            hacc[nt] += __shfl_xor(hacc[nt],16);
            hacc[nt] += __shfl_xor(hacc[nt],32);
        }
        sae += __shfl_xor(sae,16);
        sae += __shfl_xor(sae,32);
        if (lg == 0) {
            #pragma unroll
            for (int nt = 0; nt < 4; ++nt)
                hred[wj*128 + wn*64 + nt*16 + lr] = hacc[nt] + vb2v[nt]*sae;
        }
        xa0 += __shfl_xor(xa0,1);  xa1 += __shfl_xor(xa1,1);  xa2 += __shfl_xor(xa2,1);
        xa0 += __shfl_xor(xa0,2);  xa1 += __shfl_xor(xa1,2);  xa2 += __shfl_xor(xa2,2);
        xa0 += __shfl_xor(xa0,4);  xa1 += __shfl_xor(xa1,4);  xa2 += __shfl_xor(xa2,4);
        xa0 += __shfl_xor(xa0,8);  xa1 += __shfl_xor(xa1,8);  xa2 += __shfl_xor(xa2,8);
        xa0 += __shfl_xor(xa0,16); xa1 += __shfl_xor(xa1,16); xa2 += __shfl_xor(xa2,16);
        xa0 += __shfl_xor(xa0,32); xa1 += __shfl_xor(xa1,32); xa2 += __shfl_xor(xa2,32);
        if (lane == 0) { xw[w*3+0]=xa0; xw[w*3+1]=xa1; xw[w*3+2]=xa2; }
        __syncthreads();

        const float lm = ligand_mask[ii];
        if (t < HF) {
            float v = (hred[t] + hred[128+t]) * 0.01f * lm;
            atomicAdd(&out[(size_t)ii*HF + t], v);
        }
        if (t < 3) {
            float v = (xw[t] + xw[3+t] + xw[6+t] + xw[9+t]) * 0.01f * lm;
            atomicAdd(&out[(size_t)NB*NL*HF + ii*3 + t], v);
        }
    }
}

extern "C" void kernel_launch(void* const* d_in, const int* in_sizes, int n_in,
                              void* d_out, int out_size, void* d_ws, size_t ws_size,
                              hipStream_t stream) {
    const float* h_ligand     = (const float*)d_in[0];
    const float* x_ligand     = (const float*)d_in[1];
    const float* h_protein    = (const float*)d_in[2];
    const float* x_protein    = (const float*)d_in[3];
    const float* ligand_mask  = (const float*)d_in[4];
    const float* protein_mask = (const float*)d_in[5];
    const float* aW1 = (const float*)d_in[6];
    const float* ab1 = (const float*)d_in[7];
    const float* aW2 = (const float*)d_in[8];
    const float* ab2 = (const float*)d_in[9];
    const float* aW3 = (const float*)d_in[10];
    const float* ab3 = (const float*)d_in[11];
    const float* vW1 = (const float*)d_in[12];
    const float* vb1 = (const float*)d_in[13];
    const float* vW2 = (const float*)d_in[14];
    const float* vb2 = (const float*)d_in[15];
    const float* cW1 = (const float*)d_in[16];
    const float* cb1 = (const float*)d_in[17];
    const float* cW2 = (const float*)d_in[18];
    const float* cb2 = (const float*)d_in[19];

    float* Al = (float*)d_ws;                              // 512*128 f32
    float* Cl = Al + 512*HF;                               // 512*128 f32
    unsigned short* Ap  = (unsigned short*)(Cl + 512*HF);  // 4096*128 bf16
    unsigned short* Vp  = Ap + (size_t)NB*NP*HF;
    unsigned short* Cp  = Vp + (size_t)NB*NP*HF;
    unsigned short* WaT = Cp + (size_t)NB*NP*HF;           // 128*128 bf16
    unsigned short* WvT = WaT + HF*HF;
    int* counter        = (int*)(WvT + HF*HF);

    hipMemsetAsync(d_out, 0, (size_t)out_size*sizeof(float), stream);

    precompute_kernel<<<1104, 128, 0, stream>>>(
        h_ligand, h_protein, aW1, ab1, vW1, vb1, cW1, cb1, aW2, vW2,
        Al, Cl, Ap, Vp, Cp, WaT, WvT, counter);

    egnn_main_kernel<<<1024, 256, 0, stream>>>(
        x_ligand, x_protein, ligand_mask, protein_mask,
        aW1, ab2, aW3, ab3, vW1, vb2, cW1, cW2, cb2,
        Al, Cl, Ap, Vp, Cp, WaT, WvT, counter, (float*)d_out);
}

// Round 10
// 259.158 us; speedup vs baseline: 1.4906x; 1.4906x over previous
//
#include <hip/hip_runtime.h>
#include <hip/hip_bf16.h>
#include <math.h>

#define HF 128
#define NL 128
#define NP 1024
#define NB 4
#define EPSF 1e-8f
#define NITEMS 2048   // (b*128+i) x j-quarter(256)

typedef short bf16x8 __attribute__((ext_vector_type(8)));
typedef float f32x4 __attribute__((ext_vector_type(4)));

__device__ __forceinline__ float fast_rcp(float x){ return __builtin_amdgcn_rcpf(x); }
__device__ __forceinline__ float silu_f(float x){ return x*fast_rcp(1.f+__expf(-x)); }
__device__ __forceinline__ float sigmoid_f(float x){ return fast_rcp(1.f+__expf(-x)); }
__device__ __forceinline__ float tanh_f(float x){ return 1.f - 2.f*fast_rcp(1.f+__expf(2.f*x)); }
__device__ __forceinline__ unsigned short f2bf(float f){ __hip_bfloat16 h=__float2bfloat16(f); return *(unsigned short*)&h; }
__device__ __forceinline__ float bf2f(short u){ unsigned int x = ((unsigned int)(unsigned short)u)<<16; float r; __builtin_memcpy(&r,&x,4); return r; }

// ---------------------------------------------------------------------------
// Precompute: Al/Cl (f32, ligand), Ap/Vp/Cp (bf16, protein, 4 rows/block),
// WaT/WvT transposes, zero the work-queue counter.
// ---------------------------------------------------------------------------
__global__ __launch_bounds__(128) void precompute_kernel(
    const float* __restrict__ h_ligand, const float* __restrict__ h_protein,
    const float* __restrict__ aW1, const float* __restrict__ ab1,
    const float* __restrict__ vW1, const float* __restrict__ vb1,
    const float* __restrict__ cW1, const float* __restrict__ cb1,
    const float* __restrict__ aW2, const float* __restrict__ vW2,
    float* __restrict__ Al, float* __restrict__ Cl,
    unsigned short* __restrict__ Ap, unsigned short* __restrict__ Vp,
    unsigned short* __restrict__ Cp,
    unsigned short* __restrict__ WaT, unsigned short* __restrict__ WvT,
    int* __restrict__ counter)
{
    const int blk = blockIdx.x, n = threadIdx.x;
    if (blk < 64) {
        __shared__ float rows[8][HF];
        const int r0 = blk*8;
        for (int idx=n; idx<8*HF; idx+=128) rows[idx>>7][idx&127] = h_ligand[r0*HF+idx];
        __syncthreads();
        float aA[8], aC[8];
        const float bA = ab1[n], bC = cb1[n];
        #pragma unroll
        for (int r=0;r<8;++r){ aA[r]=bA; aC[r]=bC; }
        #pragma unroll 4
        for (int k=0;k<HF;++k){
            float wA = aW1[k*HF+n], wC = cW1[k*HF+n];
            #pragma unroll
            for (int r=0;r<8;++r){ aA[r]=fmaf(rows[r][k],wA,aA[r]); aC[r]=fmaf(rows[r][k],wC,aC[r]); }
        }
        #pragma unroll
        for (int r=0;r<8;++r){ Al[(r0+r)*HF+n]=aA[r]; Cl[(r0+r)*HF+n]=aC[r]; }
    } else if (blk < 1088) {
        __shared__ float rows[4][HF];
        const int r0 = (blk-64)*4;
        for (int idx=n; idx<4*HF; idx+=128) rows[idx>>7][idx&127] = h_protein[r0*HF+idx];
        __syncthreads();
        float aA[4], aV[4], aC[4];
        const float bV = vb1[n];
        #pragma unroll
        for (int r=0;r<4;++r){ aA[r]=0.f; aV[r]=bV; aC[r]=0.f; }
        #pragma unroll 2
        for (int k=0;k<HF;++k){
            float wA = aW1[(HF+k)*HF+n], wV = vW1[k*HF+n], wC = cW1[(HF+k)*HF+n];
            #pragma unroll
            for (int r=0;r<4;++r){
                float h = rows[r][k];
                aA[r]=fmaf(h,wA,aA[r]); aV[r]=fmaf(h,wV,aV[r]); aC[r]=fmaf(h,wC,aC[r]);
            }
        }
        #pragma unroll
        for (int r=0;r<4;++r){
            Ap[(r0+r)*HF+n]=f2bf(aA[r]); Vp[(r0+r)*HF+n]=f2bf(aV[r]); Cp[(r0+r)*HF+n]=f2bf(aC[r]);
        }
    } else {
        const int m = blk - 1088;        // 0..15
        if (m == 0 && n == 0) *counter = 0;
        const float* W = (m<8) ? aW2 : vW2;
        unsigned short* WT = (m<8) ? WaT : WvT;
        const int n0 = (m&7)*16;
        #pragma unroll
        for (int kb=0; kb<16; ++kb) {
            int k = kb*8 + (n>>4);
            int col = n0 + (n&15);
            WT[col*HF + k] = f2bf(W[k*HF + col]);
        }
    }
}

// ---------------------------------------------------------------------------
// Main kernel: 768 persistent blocks (3/CU) x 256 threads (4 waves, 2wj x 2wn)
// popping 2048 (ii, j-quarter) items off an atomic queue (fixes r7's 16%
// occupancy-by-imbalance).  Weights staged ONCE per block via LDS into
// register B-frags (fixes r8's global-refetch: must go through LDS or the
// allocator rematerializes the loads — r8: VGPR 84, FETCH 549 MB).
// Per item: geometry+compaction for 256 j, then r7's proven 3-barrier tile
// loop (32 compacted rows/tile, LDS A/V tiles, resident weight frags).
// ---------------------------------------------------------------------------
__global__ __launch_bounds__(256,2) void egnn_main_kernel(
    const float* __restrict__ x_ligand, const float* __restrict__ x_protein,
    const float* __restrict__ ligand_mask, const float* __restrict__ protein_mask,
    const float* __restrict__ aW1, const float* __restrict__ ab2,
    const float* __restrict__ aW3, const float* __restrict__ ab3,
    const float* __restrict__ vW1, const float* __restrict__ vb2,
    const float* __restrict__ cW1, const float* __restrict__ cW2, const float* __restrict__ cb2,
    const float* __restrict__ Al, const float* __restrict__ Cl,
    const unsigned short* __restrict__ Ap, const unsigned short* __restrict__ Vp,
    const unsigned short* __restrict__ Cp,
    const unsigned short* __restrict__ WaT, const unsigned short* __restrict__ WvT,
    int* __restrict__ counter,
    float* __restrict__ out)
{
    __shared__ __align__(16) char wt[32768];   // weight staging; later A [0,8K), V [8K,16K)
    __shared__ float ds_all[256], pme[256], dirx[256], diry[256], dirz[256];
    __shared__ unsigned short jlist[256];
    __shared__ float Al_s[HF], Cl_s[HF];
    __shared__ float aw1l[HF], cw1l[HF], vw1l[HF], cW2s[HF];
    __shared__ float attn_part[64], attn_e[32];
    __shared__ float hred[256];
    __shared__ float xw[12];
    __shared__ int nact_s, cur_s;

    const int t = threadIdx.x, lane = t&63, w = t>>6;
    const int wj = w>>1, wn = w&1;
    const int lr = lane&15, lg = lane>>4;

    // ---- block prologue (once): consts + weight staging -> register frags ----
    if (t < HF) {
        aw1l[t] = aW1[256*HF+t];
        cw1l[t] = cW1[256*HF+t];
        vw1l[t] = vW1[128*HF+t];
        cW2s[t] = cW2[t];
    }
    float ab2v[4], aw3v[4], vb2v[4];
    #pragma unroll
    for (int nt=0; nt<4; ++nt) {
        int n = wn*64 + nt*16 + lr;
        ab2v[nt] = ab2[n]; aw3v[nt] = aW3[n]; vb2v[nt] = vb2[n];
    }
    const float ab3v = ab3[0], cb2v = cb2[0];

    for (int c = t; c < 2048; c += 256) {
        int n = c >> 4, kc = c & 15;
        *(bf16x8*)(wt + n*256 + ((kc*16) ^ ((n&7)<<4))) = *(const bf16x8*)(WaT + n*HF + kc*8);
    }
    __syncthreads();
    bf16x8 wa[4][4], wv[4][4];
    #pragma unroll
    for (int nt = 0; nt < 4; ++nt) {
        int ncol = wn*64 + nt*16 + lr;
        int rb = ncol*256, sw = (ncol & 7) << 4;
        #pragma unroll
        for (int ks = 0; ks < 4; ++ks)
            wa[nt][ks] = *(bf16x8*)(wt + rb + ((lg*16 + ks*64) ^ sw));
    }
    __syncthreads();
    for (int c = t; c < 2048; c += 256) {
        int n = c >> 4, kc = c & 15;
        *(bf16x8*)(wt + n*256 + ((kc*16) ^ ((n&7)<<4))) = *(const bf16x8*)(WvT + n*HF + kc*8);
    }
    __syncthreads();
    #pragma unroll
    for (int nt = 0; nt < 4; ++nt) {
        int ncol = wn*64 + nt*16 + lr;
        int rb = ncol*256, sw = (ncol & 7) << 4;
        #pragma unroll
        for (int ks = 0; ks < 4; ++ks)
            wv[nt][ks] = *(bf16x8*)(wt + rb + ((lg*16 + ks*64) ^ sw));
    }

    const int brow = t >> 4, bcol = (t & 15)*8;   // tile build mapping
    const int crow = t >> 3, cg = t & 7;          // c-branch mapping

    // ---- work-queue loop ----
    for (;;) {
        __syncthreads();                 // prev item done; LDS reusable
        if (t == 0) cur_s = atomicAdd(counter, 1);
        __syncthreads();
        const int item = cur_s;
        if (item >= NITEMS) break;
        const int ii = item >> 2;        // b*128 + i
        const int q  = item & 3;
        const int b  = ii >> 7;
        const int jbase = q*256;

        if (t < HF) {
            Al_s[t] = Al[(size_t)ii*HF+t];
            Cl_s[t] = Cl[(size_t)ii*HF+t];
        }
        const float xl0 = x_ligand[ii*3+0], xl1 = x_ligand[ii*3+1], xl2 = x_ligand[ii*3+2];
        const float* xp = x_protein + ((size_t)b*NP + jbase)*3;
        const float* pm = protein_mask + (size_t)b*NP + jbase;
        {
            const int jj = t;
            float r0 = xl0-xp[jj*3+0], r1 = xl1-xp[jj*3+1], r2 = xl2-xp[jj*3+2];
            float ds = r0*r0+r1*r1+r2*r2;
            float dist = sqrtf(ds+EPSF);
            float inv = fast_rcp(dist+EPSF);
            float e = dist < 10.f ? 1.f : 0.f;
            ds_all[jj]=ds; pme[jj]=pm[jj]*e;
            dirx[jj]=r0*inv; diry[jj]=r1*inv; dirz[jj]=r2*inv;
        }
        __syncthreads();
        if (w == 0) {
            int base = 0;
            #pragma unroll
            for (int c=0; c<4; ++c) {
                int jj = c*64 + lane;
                bool act = pme[jj] > 0.f;
                unsigned long long m = __ballot(act);
                int pos = base + __popcll(m & ((1ull<<lane)-1ull));
                if (act) jlist[pos] = (unsigned short)jj;
                base += __popcll(m);
            }
            if (lane == 0) nact_s = base;
        }
        __syncthreads();
        const int nact = nact_s;
        if (nact == 0) continue;
        const int ntiles = (nact + 31) >> 5;

        const unsigned short* Ap_b = Ap + ((size_t)b*NP + jbase)*HF;
        const unsigned short* Vp_b = Vp + ((size_t)b*NP + jbase)*HF;
        const unsigned short* Cp_b = Cp + ((size_t)b*NP + jbase)*HF;

        float hacc[4] = {0.f,0.f,0.f,0.f};
        float sae = 0.f;
        float xa0 = 0.f, xa1 = 0.f, xa2 = 0.f;

        for (int tile = 0; tile < ntiles; ++tile) {
            const int j0 = tile*32;

            // phase 1: build A tile (compacted rows)
            #pragma unroll
            for (int m = 0; m < 2; ++m) {
                const int row = m*16 + brow;
                const int grow = j0 + row;
                const int jl = jlist[grow < nact ? grow : 0];
                const float dsv = ds_all[jl];
                bf16x8 ap = *(const bf16x8*)(Ap_b + (size_t)jl*HF + bcol);
                f32x4 al0 = *(const f32x4*)&Al_s[bcol];
                f32x4 al1 = *(const f32x4*)&Al_s[bcol+4];
                f32x4 w0  = *(const f32x4*)&aw1l[bcol];
                f32x4 w1  = *(const f32x4*)&aw1l[bcol+4];
                bf16x8 pk;
                #pragma unroll
                for (int qq = 0; qq < 4; ++qq) {
                    pk[qq]   = (short)f2bf(silu_f(al0[qq] + bf2f(ap[qq])   + dsv*w0[qq]));
                    pk[qq+4] = (short)f2bf(silu_f(al1[qq] + bf2f(ap[qq+4]) + dsv*w1[qq]));
                }
                *(bf16x8*)(wt + row*256 + ((bcol*2) ^ ((row & 7) << 4))) = pk;
            }
            __syncthreads();   // bar 1: A ready

            // phase 2: a-GEMM + attn partials; c-branch overlaps
            bf16x8 af[4];
            {
                int arow = wj*16 + lr;
                int rb = arow*256, sw = (arow & 7) << 4;
                #pragma unroll
                for (int ks = 0; ks < 4; ++ks)
                    af[ks] = *(bf16x8*)(wt + rb + ((lg*16 + ks*64) ^ sw));
            }
            f32x4 acc[4];
            #pragma unroll
            for (int nt = 0; nt < 4; ++nt) {
                acc[nt] = (f32x4){0.f,0.f,0.f,0.f};
                #pragma unroll
                for (int ks = 0; ks < 4; ++ks)
                    acc[nt] = __builtin_amdgcn_mfma_f32_16x16x32_bf16(af[ks], wa[nt][ks], acc[nt], 0,0,0);
            }
            // c-branch (VALU)
            {
                const int growc = j0 + crow;
                const bool okc = growc < nact;
                const int jlc = jlist[okc ? growc : 0];
                const float pmec = okc ? pme[jlc] : 0.f;
                const float dsc = ds_all[jlc];
                float part = 0.f;
                const unsigned short* cp = Cp_b + (size_t)jlc*HF + cg*16;
                #pragma unroll
                for (int u = 0; u < 2; ++u) {
                    const int ch = cg*16 + u*8;
                    bf16x8 cv = *(const bf16x8*)(cp + u*8);
                    f32x4 cl0 = *(const f32x4*)&Cl_s[ch];
                    f32x4 cl1 = *(const f32x4*)&Cl_s[ch+4];
                    f32x4 w0  = *(const f32x4*)&cw1l[ch];
                    f32x4 w1  = *(const f32x4*)&cw1l[ch+4];
                    f32x4 s0  = *(const f32x4*)&cW2s[ch];
                    f32x4 s1  = *(const f32x4*)&cW2s[ch+4];
                    #pragma unroll
                    for (int qq = 0; qq < 4; ++qq) {
                        part += silu_f(cl0[qq] + bf2f(cv[qq])   + dsc*w0[qq]) * s0[qq];
                        part += silu_f(cl1[qq] + bf2f(cv[qq+4]) + dsc*w1[qq]) * s1[qq];
                    }
                }
                part += __shfl_xor(part,1); part += __shfl_xor(part,2); part += __shfl_xor(part,4);
                if (cg == 0) {
                    float cw = tanh_f(part + cb2v) * pmec;
                    xa0 = fmaf(dirx[jlc], cw, xa0);
                    xa1 = fmaf(diry[jlc], cw, xa1);
                    xa2 = fmaf(dirz[jlc], cw, xa2);
                }
            }
            // attn epilogue partials
            #pragma unroll
            for (int r = 0; r < 4; ++r) {
                float p = 0.f;
                #pragma unroll
                for (int nt = 0; nt < 4; ++nt)
                    p += silu_f(acc[nt][r] + ab2v[nt]) * aw3v[nt];
                p += __shfl_xor(p,1); p += __shfl_xor(p,2);
                p += __shfl_xor(p,4); p += __shfl_xor(p,8);
                if (lr == 0) attn_part[wn*32 + wj*16 + lg*4 + r] = p;
            }
            __syncthreads();   // bar 2: attn_part ready

            // phase 3: attn_e (t<32) + build V tile
            if (t < 32) {
                const int grow = j0 + t;
                const bool ok = grow < nact;
                const int j = jlist[ok ? grow : 0];
                attn_e[t] = sigmoid_f(attn_part[t] + attn_part[32+t] + ab3v) * (ok ? pme[j] : 0.f);
            }
            #pragma unroll
            for (int m = 0; m < 2; ++m) {
                const int row = m*16 + brow;
                const int grow = j0 + row;
                const int jl = jlist[grow < nact ? grow : 0];
                const float dsv = ds_all[jl];
                bf16x8 vp = *(const bf16x8*)(Vp_b + (size_t)jl*HF + bcol);
                f32x4 w0 = *(const f32x4*)&vw1l[bcol];
                f32x4 w1 = *(const f32x4*)&vw1l[bcol+4];
                bf16x8 pk;
                #pragma unroll
                for (int qq = 0; qq < 4; ++qq) {
                    pk[qq]   = (short)f2bf(silu_f(bf2f(vp[qq])   + dsv*w0[qq]));
                    pk[qq+4] = (short)f2bf(silu_f(bf2f(vp[qq+4]) + dsv*w1[qq]));
                }
                *(bf16x8*)(wt + 8192 + row*256 + ((bcol*2) ^ ((row & 7) << 4))) = pk;
            }
            __syncthreads();   // bar 3: V + attn_e ready

            // phase 4: v-GEMM + h accumulate
            bf16x8 vf[4];
            {
                int arow = wj*16 + lr;
                int rb = 8192 + arow*256, sw = (arow & 7) << 4;
                #pragma unroll
                for (int ks = 0; ks < 4; ++ks)
                    vf[ks] = *(bf16x8*)(wt + rb + ((lg*16 + ks*64) ^ sw));
            }
            float ae[4];
            #pragma unroll
            for (int r = 0; r < 4; ++r) { ae[r] = attn_e[wj*16 + lg*4 + r]; sae += ae[r]; }
            #pragma unroll
            for (int nt = 0; nt < 4; ++nt) {
                f32x4 a = (f32x4){0.f,0.f,0.f,0.f};
                #pragma unroll
                for (int ks = 0; ks < 4; ++ks)
                    a = __builtin_amdgcn_mfma_f32_16x16x32_bf16(vf[ks], wv[nt][ks], a, 0,0,0);
                hacc[nt] += ae[0]*a[0] + ae[1]*a[1] + ae[2]*a[2] + ae[3]*a[3];
            }
        }

        // ---- per-item reductions + atomics ----
        #pragma unroll
        for (int nt = 0; nt < 4; ++nt) {
            hacc[nt] += __shfl_xor(hacc[nt],16);
            hacc[nt] += __shfl_xor(hacc[nt],32);
        }
        sae += __shfl_xor(sae,16);
        sae += __shfl_xor(sae,32);
        if (lg == 0) {
            #pragma unroll
            for (int nt = 0; nt < 4; ++nt)
                hred[wj*128 + wn*64 + nt*16 + lr] = hacc[nt] + vb2v[nt]*sae;
        }
        xa0 += __shfl_xor(xa0,1);  xa1 += __shfl_xor(xa1,1);  xa2 += __shfl_xor(xa2,1);
        xa0 += __shfl_xor(xa0,2);  xa1 += __shfl_xor(xa1,2);  xa2 += __shfl_xor(xa2,2);
        xa0 += __shfl_xor(xa0,4);  xa1 += __shfl_xor(xa1,4);  xa2 += __shfl_xor(xa2,4);
        xa0 += __shfl_xor(xa0,8);  xa1 += __shfl_xor(xa1,8);  xa2 += __shfl_xor(xa2,8);
        xa0 += __shfl_xor(xa0,16); xa1 += __shfl_xor(xa1,16); xa2 += __shfl_xor(xa2,16);
        xa0 += __shfl_xor(xa0,32); xa1 += __shfl_xor(xa1,32); xa2 += __shfl_xor(xa2,32);
        if (lane == 0) { xw[w*3+0]=xa0; xw[w*3+1]=xa1; xw[w*3+2]=xa2; }
        __syncthreads();

        const float lm = ligand_mask[ii];
        if (t < HF) {
            float v = (hred[t] + hred[128+t]) * 0.01f * lm;
            atomicAdd(&out[(size_t)ii*HF + t], v);
        }
        if (t < 3) {
            float v = (xw[t] + xw[3+t] + xw[6+t] + xw[9+t]) * 0.01f * lm;
            atomicAdd(&out[(size_t)NB*NL*HF + ii*3 + t], v);
        }
    }
}

extern "C" void kernel_launch(void* const* d_in, const int* in_sizes, int n_in,
                              void* d_out, int out_size, void* d_ws, size_t ws_size,
                              hipStream_t stream) {
    const float* h_ligand     = (const float*)d_in[0];
    const float* x_ligand     = (const float*)d_in[1];
    const float* h_protein    = (const float*)d_in[2];
    const float* x_protein    = (const float*)d_in[3];
    const float* ligand_mask  = (const float*)d_in[4];
    const float* protein_mask = (const float*)d_in[5];
    const float* aW1 = (const float*)d_in[6];
    const float* ab1 = (const float*)d_in[7];
    const float* aW2 = (const float*)d_in[8];
    const float* ab2 = (const float*)d_in[9];
    const float* aW3 = (const float*)d_in[10];
    const float* ab3 = (const float*)d_in[11];
    const float* vW1 = (const float*)d_in[12];
    const float* vb1 = (const float*)d_in[13];
    const float* vW2 = (const float*)d_in[14];
    const float* vb2 = (const float*)d_in[15];
    const float* cW1 = (const float*)d_in[16];
    const float* cb1 = (const float*)d_in[17];
    const float* cW2 = (const float*)d_in[18];
    const float* cb2 = (const float*)d_in[19];

    float* Al = (float*)d_ws;                              // 512*128 f32
    float* Cl = Al + 512*HF;                               // 512*128 f32
    unsigned short* Ap  = (unsigned short*)(Cl + 512*HF);  // 4096*128 bf16
    unsigned short* Vp  = Ap + (size_t)NB*NP*HF;
    unsigned short* Cp  = Vp + (size_t)NB*NP*HF;
    unsigned short* WaT = Cp + (size_t)NB*NP*HF;           // 128*128 bf16
    unsigned short* WvT = WaT + HF*HF;
    int* counter        = (int*)(WvT + HF*HF);

    hipMemsetAsync(d_out, 0, (size_t)out_size*sizeof(float), stream);

    precompute_kernel<<<1104, 128, 0, stream>>>(
        h_ligand, h_protein, aW1, ab1, vW1, vb1, cW1, cb1, aW2, vW2,
        Al, Cl, Ap, Vp, Cp, WaT, WvT, counter);

    egnn_main_kernel<<<768, 256, 0, stream>>>(
        x_ligand, x_protein, ligand_mask, protein_mask,
        aW1, ab2, aW3, ab3, vW1, vb2, cW1, cW2, cb2,
        Al, Cl, Ap, Vp, Cp, WaT, WvT, counter, (float*)d_out);
}

// Round 11
// 255.617 us; speedup vs baseline: 1.5112x; 1.0139x over previous
//
#include <hip/hip_runtime.h>
#include <hip/hip_bf16.h>
#include <math.h>

#define HF 128
#define NL 128
#define NP 1024
#define NB 4
#define EPSF 1e-8f
#define NITEMS 2048   // (b*128+i) x j-quarter(256)
#define OUT_N (NB*NL*HF + NB*NL*3)

typedef short bf16x8 __attribute__((ext_vector_type(8)));
typedef float f32x4 __attribute__((ext_vector_type(4)));

__device__ __forceinline__ float fast_rcp(float x){ return __builtin_amdgcn_rcpf(x); }
__device__ __forceinline__ float silu_f(float x){ return x*fast_rcp(1.f+__expf(-x)); }
__device__ __forceinline__ float sigmoid_f(float x){ return fast_rcp(1.f+__expf(-x)); }
__device__ __forceinline__ float tanh_f(float x){ return 1.f - 2.f*fast_rcp(1.f+__expf(2.f*x)); }
__device__ __forceinline__ unsigned short f2bf(float f){ __hip_bfloat16 h=__float2bfloat16(f); return *(unsigned short*)&h; }
__device__ __forceinline__ float bf2f(short u){ unsigned int x = ((unsigned int)(unsigned short)u)<<16; float r; __builtin_memcpy(&r,&x,4); return r; }

// ---------------------------------------------------------------------------
// Precompute: Al/Cl (f32), Ap/Vp/Cp (bf16), WaT/WvT transposes, zero the
// work-queue counter AND d_out (re-poisoned to 0xAA before every replay).
// ---------------------------------------------------------------------------
__global__ __launch_bounds__(128) void precompute_kernel(
    const float* __restrict__ h_ligand, const float* __restrict__ h_protein,
    const float* __restrict__ aW1, const float* __restrict__ ab1,
    const float* __restrict__ vW1, const float* __restrict__ vb1,
    const float* __restrict__ cW1, const float* __restrict__ cb1,
    const float* __restrict__ aW2, const float* __restrict__ vW2,
    float* __restrict__ Al, float* __restrict__ Cl,
    unsigned short* __restrict__ Ap, unsigned short* __restrict__ Vp,
    unsigned short* __restrict__ Cp,
    unsigned short* __restrict__ WaT, unsigned short* __restrict__ WvT,
    int* __restrict__ counter, float* __restrict__ out)
{
    const int blk = blockIdx.x, n = threadIdx.x;
    {   // zero d_out (disjoint coverage across blocks)
        int gid = blk*128 + n;
        if (gid < OUT_N) out[gid] = 0.f;
    }
    if (blk < 64) {
        __shared__ float rows[8][HF];
        const int r0 = blk*8;
        for (int idx=n; idx<8*HF; idx+=128) rows[idx>>7][idx&127] = h_ligand[r0*HF+idx];
        __syncthreads();
        float aA[8], aC[8];
        const float bA = ab1[n], bC = cb1[n];
        #pragma unroll
        for (int r=0;r<8;++r){ aA[r]=bA; aC[r]=bC; }
        #pragma unroll 4
        for (int k=0;k<HF;++k){
            float wA = aW1[k*HF+n], wC = cW1[k*HF+n];
            #pragma unroll
            for (int r=0;r<8;++r){ aA[r]=fmaf(rows[r][k],wA,aA[r]); aC[r]=fmaf(rows[r][k],wC,aC[r]); }
        }
        #pragma unroll
        for (int r=0;r<8;++r){ Al[(r0+r)*HF+n]=aA[r]; Cl[(r0+r)*HF+n]=aC[r]; }
    } else if (blk < 1088) {
        __shared__ float rows[4][HF];
        const int r0 = (blk-64)*4;
        for (int idx=n; idx<4*HF; idx+=128) rows[idx>>7][idx&127] = h_protein[r0*HF+idx];
        __syncthreads();
        float aA[4], aV[4], aC[4];
        const float bV = vb1[n];
        #pragma unroll
        for (int r=0;r<4;++r){ aA[r]=0.f; aV[r]=bV; aC[r]=0.f; }
        #pragma unroll 2
        for (int k=0;k<HF;++k){
            float wA = aW1[(HF+k)*HF+n], wV = vW1[k*HF+n], wC = cW1[(HF+k)*HF+n];
            #pragma unroll
            for (int r=0;r<4;++r){
                float h = rows[r][k];
                aA[r]=fmaf(h,wA,aA[r]); aV[r]=fmaf(h,wV,aV[r]); aC[r]=fmaf(h,wC,aC[r]);
            }
        }
        #pragma unroll
        for (int r=0;r<4;++r){
            Ap[(r0+r)*HF+n]=f2bf(aA[r]); Vp[(r0+r)*HF+n]=f2bf(aV[r]); Cp[(r0+r)*HF+n]=f2bf(aC[r]);
        }
    } else {
        const int m = blk - 1088;        // 0..15
        if (m == 0 && n == 0) *counter = 0;
        const float* W = (m<8) ? aW2 : vW2;
        unsigned short* WT = (m<8) ? WaT : WvT;
        const int n0 = (m&7)*16;
        #pragma unroll
        for (int kb=0; kb<16; ++kb) {
            int k = kb*8 + (n>>4);
            int col = n0 + (n&15);
            WT[col*HF + k] = f2bf(W[k*HF + col]);
        }
    }
}

// ---------------------------------------------------------------------------
// Main: 1024 persistent blocks (4/CU: LDS ~28 KB, VGPR<=128) x 256 threads
// (4 waves, 2wj x 2wn) popping 2048 (ii, j-quarter) items off atomic queue.
// Weights staged per block via LDS in TWO 16 KB halves (wn==h waves grab
// their B-frags per half) -> register-resident wa/wv (zero-spill recipe).
// Per-lane epilogue consts (ab2/aW3/vb2) live in LDS to stay under the
// 128-VGPR 4-block boundary (r10: 133 live -> 23 MB scratch writes).
// ---------------------------------------------------------------------------
__global__ __launch_bounds__(256,2) void egnn_main_kernel(
    const float* __restrict__ x_ligand, const float* __restrict__ x_protein,
    const float* __restrict__ ligand_mask, const float* __restrict__ protein_mask,
    const float* __restrict__ aW1, const float* __restrict__ ab2,
    const float* __restrict__ aW3, const float* __restrict__ ab3,
    const float* __restrict__ vW1, const float* __restrict__ vb2,
    const float* __restrict__ cW1, const float* __restrict__ cW2, const float* __restrict__ cb2,
    const float* __restrict__ Al, const float* __restrict__ Cl,
    const unsigned short* __restrict__ Ap, const unsigned short* __restrict__ Vp,
    const unsigned short* __restrict__ Cp,
    const unsigned short* __restrict__ WaT, const unsigned short* __restrict__ WvT,
    int* __restrict__ counter,
    float* __restrict__ out)
{
    __shared__ __align__(16) char wt[16384];   // weight-half staging; later A [0,8K), V [8K,16K)
    __shared__ float ds_all[256], pme[256], dirx[256], diry[256], dirz[256];
    __shared__ unsigned short jlist[256];
    __shared__ float Al_s[HF], Cl_s[HF];
    __shared__ float aw1l[HF], cw1l[HF], vw1l[HF], cW2s[HF];
    __shared__ float2 aa3[HF];                 // {ab2, aW3}
    __shared__ float vb2s[HF];
    __shared__ float attn_part[64], attn_e[32];
    __shared__ float hred[256];
    __shared__ float xw[12];
    __shared__ int nact_s, cur_s;

    const int t = threadIdx.x, lane = t&63, w = t>>6;
    const int wj = w>>1, wn = w&1;
    const int lr = lane&15, lg = lane>>4;

    // ---- block prologue (once): consts + two-half weight staging ----
    if (t < HF) {
        aw1l[t] = aW1[256*HF+t];
        cw1l[t] = cW1[256*HF+t];
        vw1l[t] = vW1[128*HF+t];
        cW2s[t] = cW2[t];
        aa3[t]  = make_float2(ab2[t], aW3[t]);
        vb2s[t] = vb2[t];
    }
    const float ab3v = ab3[0], cb2v = cb2[0];

    bf16x8 wa[4][4], wv[4][4];
    #pragma unroll
    for (int h = 0; h < 2; ++h) {
        __syncthreads();
        for (int c = t; c < 1024; c += 256) {          // 64 ncols x 16 chunks
            int nloc = c >> 4, kc = c & 15;
            *(bf16x8*)(wt + nloc*256 + ((kc*16) ^ ((nloc&7)<<4))) =
                *(const bf16x8*)(WaT + (size_t)(h*64 + nloc)*HF + kc*8);
        }
        __syncthreads();
        if (wn == h) {
            #pragma unroll
            for (int nt = 0; nt < 4; ++nt) {
                int nloc = nt*16 + lr;
                int rb = nloc*256, sw = (nloc & 7) << 4;
                #pragma unroll
                for (int ks = 0; ks < 4; ++ks)
                    wa[nt][ks] = *(bf16x8*)(wt + rb + ((lg*16 + ks*64) ^ sw));
            }
        }
    }
    #pragma unroll
    for (int h = 0; h < 2; ++h) {
        __syncthreads();
        for (int c = t; c < 1024; c += 256) {
            int nloc = c >> 4, kc = c & 15;
            *(bf16x8*)(wt + nloc*256 + ((kc*16) ^ ((nloc&7)<<4))) =
                *(const bf16x8*)(WvT + (size_t)(h*64 + nloc)*HF + kc*8);
        }
        __syncthreads();
        if (wn == h) {
            #pragma unroll
            for (int nt = 0; nt < 4; ++nt) {
                int nloc = nt*16 + lr;
                int rb = nloc*256, sw = (nloc & 7) << 4;
                #pragma unroll
                for (int ks = 0; ks < 4; ++ks)
                    wv[nt][ks] = *(bf16x8*)(wt + rb + ((lg*16 + ks*64) ^ sw));
            }
        }
    }

    const int brow = t >> 4, bcol = (t & 15)*8;   // tile build mapping
    const int crow = t >> 3, cg = t & 7;          // c-branch mapping

    // ---- work-queue loop ----
    for (;;) {
        __syncthreads();                 // prev item done; LDS reusable
        if (t == 0) cur_s = atomicAdd(counter, 1);
        __syncthreads();
        const int item = cur_s;
        if (item >= NITEMS) break;
        const int ii = item >> 2;        // b*128 + i
        const int q  = item & 3;
        const int b  = ii >> 7;
        const int jbase = q*256;

        if (t < HF) {
            Al_s[t] = Al[(size_t)ii*HF+t];
            Cl_s[t] = Cl[(size_t)ii*HF+t];
        }
        const float xl0 = x_ligand[ii*3+0], xl1 = x_ligand[ii*3+1], xl2 = x_ligand[ii*3+2];
        const float* xp = x_protein + ((size_t)b*NP + jbase)*3;
        const float* pm = protein_mask + (size_t)b*NP + jbase;
        {
            const int jj = t;
            float r0 = xl0-xp[jj*3+0], r1 = xl1-xp[jj*3+1], r2 = xl2-xp[jj*3+2];
            float ds = r0*r0+r1*r1+r2*r2;
            float dist = sqrtf(ds+EPSF);
            float inv = fast_rcp(dist+EPSF);
            float e = dist < 10.f ? 1.f : 0.f;
            ds_all[jj]=ds; pme[jj]=pm[jj]*e;
            dirx[jj]=r0*inv; diry[jj]=r1*inv; dirz[jj]=r2*inv;
        }
        __syncthreads();
        if (w == 0) {
            int base = 0;
            #pragma unroll
            for (int c=0; c<4; ++c) {
                int jj = c*64 + lane;
                bool act = pme[jj] > 0.f;
                unsigned long long m = __ballot(act);
                int pos = base + __popcll(m & ((1ull<<lane)-1ull));
                if (act) jlist[pos] = (unsigned short)jj;
                base += __popcll(m);
            }
            if (lane == 0) nact_s = base;
        }
        __syncthreads();
        const int nact = nact_s;
        if (nact == 0) continue;
        const int ntiles = (nact + 31) >> 5;

        const unsigned short* Ap_b = Ap + ((size_t)b*NP + jbase)*HF;
        const unsigned short* Vp_b = Vp + ((size_t)b*NP + jbase)*HF;
        const unsigned short* Cp_b = Cp + ((size_t)b*NP + jbase)*HF;

        float hacc[4] = {0.f,0.f,0.f,0.f};
        float sae = 0.f;
        float xa0 = 0.f, xa1 = 0.f, xa2 = 0.f;

        for (int tile = 0; tile < ntiles; ++tile) {
            const int j0 = tile*32;

            // phase 1: build A tile (compacted rows)
            #pragma unroll
            for (int m = 0; m < 2; ++m) {
                const int row = m*16 + brow;
                const int grow = j0 + row;
                const int jl = jlist[grow < nact ? grow : 0];
                const float dsv = ds_all[jl];
                bf16x8 ap = *(const bf16x8*)(Ap_b + (size_t)jl*HF + bcol);
                f32x4 al0 = *(const f32x4*)&Al_s[bcol];
                f32x4 al1 = *(const f32x4*)&Al_s[bcol+4];
                f32x4 w0  = *(const f32x4*)&aw1l[bcol];
                f32x4 w1  = *(const f32x4*)&aw1l[bcol+4];
                bf16x8 pk;
                #pragma unroll
                for (int qq = 0; qq < 4; ++qq) {
                    pk[qq]   = (short)f2bf(silu_f(al0[qq] + bf2f(ap[qq])   + dsv*w0[qq]));
                    pk[qq+4] = (short)f2bf(silu_f(al1[qq] + bf2f(ap[qq+4]) + dsv*w1[qq]));
                }
                *(bf16x8*)(wt + row*256 + ((bcol*2) ^ ((row & 7) << 4))) = pk;
            }
            __syncthreads();   // bar 1: A ready

            // phase 2: a-GEMM + attn partials; c-branch overlaps
            bf16x8 af[4];
            {
                int arow = wj*16 + lr;
                int rb = arow*256, sw = (arow & 7) << 4;
                #pragma unroll
                for (int ks = 0; ks < 4; ++ks)
                    af[ks] = *(bf16x8*)(wt + rb + ((lg*16 + ks*64) ^ sw));
            }
            f32x4 acc[4];
            #pragma unroll
            for (int nt = 0; nt < 4; ++nt) {
                acc[nt] = (f32x4){0.f,0.f,0.f,0.f};
                #pragma unroll
                for (int ks = 0; ks < 4; ++ks)
                    acc[nt] = __builtin_amdgcn_mfma_f32_16x16x32_bf16(af[ks], wa[nt][ks], acc[nt], 0,0,0);
            }
            // c-branch (VALU)
            {
                const int growc = j0 + crow;
                const bool okc = growc < nact;
                const int jlc = jlist[okc ? growc : 0];
                const float pmec = okc ? pme[jlc] : 0.f;
                const float dsc = ds_all[jlc];
                float part = 0.f;
                const unsigned short* cp = Cp_b + (size_t)jlc*HF + cg*16;
                #pragma unroll
                for (int u = 0; u < 2; ++u) {
                    const int ch = cg*16 + u*8;
                    bf16x8 cv = *(const bf16x8*)(cp + u*8);
                    f32x4 cl0 = *(const f32x4*)&Cl_s[ch];
                    f32x4 cl1 = *(const f32x4*)&Cl_s[ch+4];
                    f32x4 w0  = *(const f32x4*)&cw1l[ch];
                    f32x4 w1  = *(const f32x4*)&cw1l[ch+4];
                    f32x4 s0  = *(const f32x4*)&cW2s[ch];
                    f32x4 s1  = *(const f32x4*)&cW2s[ch+4];
                    #pragma unroll
                    for (int qq = 0; qq < 4; ++qq) {
                        part += silu_f(cl0[qq] + bf2f(cv[qq])   + dsc*w0[qq]) * s0[qq];
                        part += silu_f(cl1[qq] + bf2f(cv[qq+4]) + dsc*w1[qq]) * s1[qq];
                    }
                }
                part += __shfl_xor(part,1); part += __shfl_xor(part,2); part += __shfl_xor(part,4);
                if (cg == 0) {
                    float cw = tanh_f(part + cb2v) * pmec;
                    xa0 = fmaf(dirx[jlc], cw, xa0);
                    xa1 = fmaf(diry[jlc], cw, xa1);
                    xa2 = fmaf(dirz[jlc], cw, xa2);
                }
            }
            // attn epilogue partials (consts from LDS: aa3 = {ab2, aW3})
            #pragma unroll
            for (int r = 0; r < 4; ++r) {
                float p = 0.f;
                #pragma unroll
                for (int nt = 0; nt < 4; ++nt) {
                    float2 c2 = aa3[wn*64 + nt*16 + lr];
                    p += silu_f(acc[nt][r] + c2.x) * c2.y;
                }
                p += __shfl_xor(p,1); p += __shfl_xor(p,2);
                p += __shfl_xor(p,4); p += __shfl_xor(p,8);
                if (lr == 0) attn_part[wn*32 + wj*16 + lg*4 + r] = p;
            }
            __syncthreads();   // bar 2: attn_part ready

            // phase 3: attn_e (t<32) + build V tile
            if (t < 32) {
                const int grow = j0 + t;
                const bool ok = grow < nact;
                const int j = jlist[ok ? grow : 0];
                attn_e[t] = sigmoid_f(attn_part[t] + attn_part[32+t] + ab3v) * (ok ? pme[j] : 0.f);
            }
            #pragma unroll
            for (int m = 0; m < 2; ++m) {
                const int row = m*16 + brow;
                const int grow = j0 + row;
                const int jl = jlist[grow < nact ? grow : 0];
                const float dsv = ds_all[jl];
                bf16x8 vp = *(const bf16x8*)(Vp_b + (size_t)jl*HF + bcol);
                f32x4 w0 = *(const f32x4*)&vw1l[bcol];
                f32x4 w1 = *(const f32x4*)&vw1l[bcol+4];
                bf16x8 pk;
                #pragma unroll
                for (int qq = 0; qq < 4; ++qq) {
                    pk[qq]   = (short)f2bf(silu_f(bf2f(vp[qq])   + dsv*w0[qq]));
                    pk[qq+4] = (short)f2bf(silu_f(bf2f(vp[qq+4]) + dsv*w1[qq]));
                }
                *(bf16x8*)(wt + 8192 + row*256 + ((bcol*2) ^ ((row & 7) << 4))) = pk;
            }
            __syncthreads();   // bar 3: V + attn_e ready

            // phase 4: v-GEMM + h accumulate
            bf16x8 vf[4];
            {
                int arow = wj*16 + lr;
                int rb = 8192 + arow*256, sw = (arow & 7) << 4;
                #pragma unroll
                for (int ks = 0; ks < 4; ++ks)
                    vf[ks] = *(bf16x8*)(wt + rb + ((lg*16 + ks*64) ^ sw));
            }
            float ae[4];
            #pragma unroll
            for (int r = 0; r < 4; ++r) { ae[r] = attn_e[wj*16 + lg*4 + r]; sae += ae[r]; }
            #pragma unroll
            for (int nt = 0; nt < 4; ++nt) {
                f32x4 a = (f32x4){0.f,0.f,0.f,0.f};
                #pragma unroll
                for (int ks = 0; ks < 4; ++ks)
                    a = __builtin_amdgcn_mfma_f32_16x16x32_bf16(vf[ks], wv[nt][ks], a, 0,0,0);
                hacc[nt] += ae[0]*a[0] + ae[1]*a[1] + ae[2]*a[2] + ae[3]*a[3];
            }
        }

        // ---- per-item reductions + atomics ----
        #pragma unroll
        for (int nt = 0; nt < 4; ++nt) {
            hacc[nt] += __shfl_xor(hacc[nt],16);
            hacc[nt] += __shfl_xor(hacc[nt],32);
        }
        sae += __shfl_xor(sae,16);
        sae += __shfl_xor(sae,32);
        if (lg == 0) {
            #pragma unroll
            for (int nt = 0; nt < 4; ++nt)
                hred[wj*128 + wn*64 + nt*16 + lr] = hacc[nt] + vb2s[wn*64 + nt*16 + lr]*sae;
        }
        xa0 += __shfl_xor(xa0,1);  xa1 += __shfl_xor(xa1,1);  xa2 += __shfl_xor(xa2,1);
        xa0 += __shfl_xor(xa0,2);  xa1 += __shfl_xor(xa1,2);  xa2 += __shfl_xor(xa2,2);
        xa0 += __shfl_xor(xa0,4);  xa1 += __shfl_xor(xa1,4);  xa2 += __shfl_xor(xa2,4);
        xa0 += __shfl_xor(xa0,8);  xa1 += __shfl_xor(xa1,8);  xa2 += __shfl_xor(xa2,8);
        xa0 += __shfl_xor(xa0,16); xa1 += __shfl_xor(xa1,16); xa2 += __shfl_xor(xa2,16);
        xa0 += __shfl_xor(xa0,32); xa1 += __shfl_xor(xa1,32); xa2 += __shfl_xor(xa2,32);
        if (lane == 0) { xw[w*3+0]=xa0; xw[w*3+1]=xa1; xw[w*3+2]=xa2; }
        __syncthreads();

        const float lm = ligand_mask[ii];
        if (t < HF) {
            float v = (hred[t] + hred[128+t]) * 0.01f * lm;
            atomicAdd(&out[(size_t)ii*HF + t], v);
        }
        if (t < 3) {
            float v = (xw[t] + xw[3+t] + xw[6+t] + xw[9+t]) * 0.01f * lm;
            atomicAdd(&out[(size_t)NB*NL*HF + ii*3 + t], v);
        }
    }
}

extern "C" void kernel_launch(void* const* d_in, const int* in_sizes, int n_in,
                              void* d_out, int out_size, void* d_ws, size_t ws_size,
                              hipStream_t stream) {
    const float* h_ligand     = (const float*)d_in[0];
    const float* x_ligand     = (const float*)d_in[1];
    const float* h_protein    = (const float*)d_in[2];
    const float* x_protein    = (const float*)d_in[3];
    const float* ligand_mask  = (const float*)d_in[4];
    const float* protein_mask = (const float*)d_in[5];
    const float* aW1 = (const float*)d_in[6];
    const float* ab1 = (const float*)d_in[7];
    const float* aW2 = (const float*)d_in[8];
    const float* ab2 = (const float*)d_in[9];
    const float* aW3 = (const float*)d_in[10];
    const float* ab3 = (const float*)d_in[11];
    const float* vW1 = (const float*)d_in[12];
    const float* vb1 = (const float*)d_in[13];
    const float* vW2 = (const float*)d_in[14];
    const float* vb2 = (const float*)d_in[15];
    const float* cW1 = (const float*)d_in[16];
    const float* cb1 = (const float*)d_in[17];
    const float* cW2 = (const float*)d_in[18];
    const float* cb2 = (const float*)d_in[19];

    float* Al = (float*)d_ws;                              // 512*128 f32
    float* Cl = Al + 512*HF;                               // 512*128 f32
    unsigned short* Ap  = (unsigned short*)(Cl + 512*HF);  // 4096*128 bf16
    unsigned short* Vp  = Ap + (size_t)NB*NP*HF;
    unsigned short* Cp  = Vp + (size_t)NB*NP*HF;
    unsigned short* WaT = Cp + (size_t)NB*NP*HF;           // 128*128 bf16
    unsigned short* WvT = WaT + HF*HF;
    int* counter        = (int*)(WvT + HF*HF);

    precompute_kernel<<<1104, 128, 0, stream>>>(
        h_ligand, h_protein, aW1, ab1, vW1, vb1, cW1, cb1, aW2, vW2,
        Al, Cl, Ap, Vp, Cp, WaT, WvT, counter, (float*)d_out);

    egnn_main_kernel<<<1024, 256, 0, stream>>>(
        x_ligand, x_protein, ligand_mask, protein_mask,
        aW1, ab2, aW3, ab3, vW1, vb2, cW1, cW2, cb2,
        Al, Cl, Ap, Vp, Cp, WaT, WvT, counter, (float*)d_out);
}

// Round 12
// 251.566 us; speedup vs baseline: 1.5356x; 1.0161x over previous
//
#include <hip/hip_runtime.h>
#include <hip/hip_bf16.h>
#include <math.h>

#define HF 128
#define NL 128
#define NP 1024
#define NB 4
#define EPSF 1e-8f

typedef short bf16x8 __attribute__((ext_vector_type(8)));
typedef float f32x4 __attribute__((ext_vector_type(4)));

__device__ __forceinline__ float fast_rcp(float x){ return __builtin_amdgcn_rcpf(x); }
__device__ __forceinline__ float silu_f(float x){ return x*fast_rcp(1.f+__expf(-x)); }
__device__ __forceinline__ float sigmoid_f(float x){ return fast_rcp(1.f+__expf(-x)); }
__device__ __forceinline__ float tanh_f(float x){ return 1.f - 2.f*fast_rcp(1.f+__expf(2.f*x)); }
__device__ __forceinline__ unsigned short f2bf(float f){ __hip_bfloat16 h=__float2bfloat16(f); return *(unsigned short*)&h; }
__device__ __forceinline__ float bf2f(short u){ unsigned int x = ((unsigned int)(unsigned short)u)<<16; float r; __builtin_memcpy(&r,&x,4); return r; }

// ---------------------------------------------------------------------------
// Precompute (r7's proven version):
//   Al/Cl (f32, ligand), Ap/Vp/Cp (bf16, protein), WaT/WvT transposes.
// ---------------------------------------------------------------------------
__global__ __launch_bounds__(128) void precompute_kernel(
    const float* __restrict__ h_ligand, const float* __restrict__ h_protein,
    const float* __restrict__ aW1, const float* __restrict__ ab1,
    const float* __restrict__ vW1, const float* __restrict__ vb1,
    const float* __restrict__ cW1, const float* __restrict__ cb1,
    const float* __restrict__ aW2, const float* __restrict__ vW2,
    float* __restrict__ Al, float* __restrict__ Cl,
    unsigned short* __restrict__ Ap, unsigned short* __restrict__ Vp,
    unsigned short* __restrict__ Cp,
    unsigned short* __restrict__ WaT, unsigned short* __restrict__ WvT)
{
    const int blk = blockIdx.x, n = threadIdx.x;
    if (blk < 64) {
        __shared__ float rows[8][HF];
        const int r0 = blk*8;
        for (int idx=n; idx<8*HF; idx+=128) rows[idx>>7][idx&127] = h_ligand[r0*HF+idx];
        __syncthreads();
        float aA[8], aC[8];
        const float bA = ab1[n], bC = cb1[n];
        #pragma unroll
        for (int r=0;r<8;++r){ aA[r]=bA; aC[r]=bC; }
        #pragma unroll 4
        for (int k=0;k<HF;++k){
            float wA = aW1[k*HF+n], wC = cW1[k*HF+n];
            #pragma unroll
            for (int r=0;r<8;++r){ aA[r]=fmaf(rows[r][k],wA,aA[r]); aC[r]=fmaf(rows[r][k],wC,aC[r]); }
        }
        #pragma unroll
        for (int r=0;r<8;++r){ Al[(r0+r)*HF+n]=aA[r]; Cl[(r0+r)*HF+n]=aC[r]; }
    } else if (blk < 576) {
        __shared__ float rows[8][HF];
        const int r0 = (blk-64)*8;
        for (int idx=n; idx<8*HF; idx+=128) rows[idx>>7][idx&127] = h_protein[r0*HF+idx];
        __syncthreads();
        float aA[8], aV[8], aC[8];
        const float bV = vb1[n];
        #pragma unroll
        for (int r=0;r<8;++r){ aA[r]=0.f; aV[r]=bV; aC[r]=0.f; }
        #pragma unroll 2
        for (int k=0;k<HF;++k){
            float wA = aW1[(HF+k)*HF+n], wV = vW1[k*HF+n], wC = cW1[(HF+k)*HF+n];
            #pragma unroll
            for (int r=0;r<8;++r){
                float h = rows[r][k];
                aA[r]=fmaf(h,wA,aA[r]); aV[r]=fmaf(h,wV,aV[r]); aC[r]=fmaf(h,wC,aC[r]);
            }
        }
        #pragma unroll
        for (int r=0;r<8;++r){
            Ap[(r0+r)*HF+n]=f2bf(aA[r]); Vp[(r0+r)*HF+n]=f2bf(aV[r]); Cp[(r0+r)*HF+n]=f2bf(aC[r]);
        }
    } else {
        const int m = blk - 576;
        const float* W = (m<8) ? aW2 : vW2;
        unsigned short* WT = (m<8) ? WaT : WvT;
        const int n0 = (m&7)*16;
        #pragma unroll
        for (int kb=0; kb<16; ++kb) {
            int k = kb*8 + (n>>4);
            int col = n0 + (n&15);
            WT[col*HF + k] = f2bf(W[k*HF + col]);
        }
    }
}

// ---------------------------------------------------------------------------
// Main kernel = r7 (best measured: 124.8us) + global_load_lds prefetch.
// Occupancy is register-capped at 2 blocks/CU (weights = 128 AGPRs/wave on
// the unified file) — r8-r11 proved more blocks don't help.  The remaining
// stall is per-tile exposed L2 latency on the jlist-gathered Ap/Vp rows.
// Fix: double-buffered raw LDS prefetch via global_load_lds (zero VGPR):
// at phase 1 of tile t we issue the gathers for tile t+1; the vmcnt(0)
// drain at the next barrier completes them a full tile early, so phases
// 1/3 read LDS instead of stalling on L2.
// LDS map (64000 B total):
//   [0,32768)  : weight staging (prologue) -> A-tile [0,8K), V-tile [8K,16K),
//                rawA dbuf [16K,32K)  ;  hred aliased at [0,1K) (epilogue)
//   [32768..)  : geometry (ds/pme/dir*), jlist, consts, attn, xw, nact
//   [47616,64000): rawV dbuf
// ---------------------------------------------------------------------------
__global__ __launch_bounds__(256,2) void egnn_main_kernel(
    const float* __restrict__ x_ligand, const float* __restrict__ x_protein,
    const float* __restrict__ ligand_mask, const float* __restrict__ protein_mask,
    const float* __restrict__ aW1, const float* __restrict__ ab2,
    const float* __restrict__ aW3, const float* __restrict__ ab3,
    const float* __restrict__ vW1, const float* __restrict__ vb2,
    const float* __restrict__ cW1, const float* __restrict__ cW2, const float* __restrict__ cb2,
    const float* __restrict__ Al, const float* __restrict__ Cl,
    const unsigned short* __restrict__ Ap, const unsigned short* __restrict__ Vp,
    const unsigned short* __restrict__ Cp,
    const unsigned short* __restrict__ WaT, const unsigned short* __restrict__ WvT,
    float* __restrict__ out)
{
    __shared__ __align__(16) char smem[64000];
    float* ds_all = (float*)(smem + 32768);            // [512]
    float* pme    = (float*)(smem + 34816);            // [512]
    float* dirx   = (float*)(smem + 36864);
    float* diry   = (float*)(smem + 38912);
    float* dirz   = (float*)(smem + 40960);
    unsigned short* jlist = (unsigned short*)(smem + 43008); // [512]
    float* Al_s   = (float*)(smem + 44032);            // [128] each
    float* Cl_s   = (float*)(smem + 44544);
    float* aw1l   = (float*)(smem + 45056);
    float* cw1l   = (float*)(smem + 45568);
    float* vw1l   = (float*)(smem + 46080);
    float* cW2s   = (float*)(smem + 46592);
    float* attn_part = (float*)(smem + 47104);         // [64]
    float* attn_e = (float*)(smem + 47360);            // [32]
    float* xw     = (float*)(smem + 47488);            // [12]
    int* nact_p   = (int*)(smem + 47536);
    char* rawA    = smem + 16384;                      // dbuf 2 x 8192
    char* rawV    = smem + 47616;                      // dbuf 2 x 8192
    float* hred   = (float*)smem;                      // [256], aliased on A-tile (epilogue only)

    const int t = threadIdx.x, lane = t&63, w = t>>6;
    const int wj = w>>1, wn = w&1;
    const int lr = lane&15, lg = lane>>4;
    const int bi = blockIdx.x;
    const int half = bi & 1;
    const int ii = bi >> 1;
    const int b = ii >> 7;
    const int jbase = half*512;

    // ---- prologue: geometry + consts; stage WaT ----
    const float xl0 = x_ligand[ii*3+0], xl1 = x_ligand[ii*3+1], xl2 = x_ligand[ii*3+2];
    const float* xp = x_protein + ((size_t)b*NP + jbase)*3;
    const float* pm = protein_mask + (size_t)b*NP + jbase;
    #pragma unroll
    for (int q=0; q<2; ++q) {
        int jj = q*256 + t;
        float r0 = xl0-xp[jj*3+0], r1 = xl1-xp[jj*3+1], r2 = xl2-xp[jj*3+2];
        float ds = r0*r0+r1*r1+r2*r2;
        float dist = sqrtf(ds+EPSF);
        float inv = fast_rcp(dist+EPSF);
        float e = dist < 10.f ? 1.f : 0.f;
        ds_all[jj]=ds; pme[jj]=pm[jj]*e;
        dirx[jj]=r0*inv; diry[jj]=r1*inv; dirz[jj]=r2*inv;
    }
    if (t < HF) {
        Al_s[t] = Al[(size_t)ii*HF+t];
        Cl_s[t] = Cl[(size_t)ii*HF+t];
        aw1l[t] = aW1[256*HF+t];
        cw1l[t] = cW1[256*HF+t];
        vw1l[t] = vW1[128*HF+t];
        cW2s[t] = cW2[t];
    }
    float ab2v[4], aw3v[4], vb2v[4];
    #pragma unroll
    for (int nt=0; nt<4; ++nt) {
        int n = wn*64 + nt*16 + lr;
        ab2v[nt] = ab2[n]; aw3v[nt] = aW3[n]; vb2v[nt] = vb2[n];
    }
    const float ab3v = ab3[0], cb2v = cb2[0];

    for (int c = t; c < 2048; c += 256) {
        int n = c >> 4, kc = c & 15;
        *(bf16x8*)(smem + n*256 + ((kc*16) ^ ((n&7)<<4))) = *(const bf16x8*)(WaT + n*HF + kc*8);
    }
    __syncthreads();   // WaT staged; geometry ready

    if (w == 0) {      // compaction
        int base = 0;
        for (int c=0; c<8; ++c) {
            int jj = c*64 + lane;
            bool act = pme[jj] > 0.f;
            unsigned long long m = __ballot(act);
            int pos = base + __popcll(m & ((1ull<<lane)-1ull));
            if (act) jlist[pos] = (unsigned short)jj;
            base += __popcll(m);
        }
        if (lane == 0) *nact_p = base;
    }
    bf16x8 wa[4][4], wv[4][4];
    #pragma unroll
    for (int nt = 0; nt < 4; ++nt) {
        int ncol = wn*64 + nt*16 + lr;
        int rb = ncol*256, sw = (ncol & 7) << 4;
        #pragma unroll
        for (int ks = 0; ks < 4; ++ks)
            wa[nt][ks] = *(bf16x8*)(smem + rb + ((lg*16 + ks*64) ^ sw));
    }
    __syncthreads();
    for (int c = t; c < 2048; c += 256) {
        int n = c >> 4, kc = c & 15;
        *(bf16x8*)(smem + n*256 + ((kc*16) ^ ((n&7)<<4))) = *(const bf16x8*)(WvT + n*HF + kc*8);
    }
    __syncthreads();
    #pragma unroll
    for (int nt = 0; nt < 4; ++nt) {
        int ncol = wn*64 + nt*16 + lr;
        int rb = ncol*256, sw = (ncol & 7) << 4;
        #pragma unroll
        for (int ks = 0; ks < 4; ++ks)
            wv[nt][ks] = *(bf16x8*)(smem + rb + ((lg*16 + ks*64) ^ sw));
    }
    __syncthreads();   // weights in regs; lo LDS free; nact visible

    const int nact = *nact_p;
    const int ntiles = (nact + 31) >> 5;

    const unsigned short* Ap_b = Ap + ((size_t)b*NP + jbase)*HF;
    const unsigned short* Vp_b = Vp + ((size_t)b*NP + jbase)*HF;
    const unsigned short* Cp_b = Cp + ((size_t)b*NP + jbase)*HF;

    // gather 32 compacted rows (256 B each) of arr into rawbase via
    // global_load_lds: per-lane global src, linear wave-uniform LDS dst.
    // 4 rows / instruction, 2 instructions / wave.
    auto pf = [&](const unsigned short* arr, char* rawbase, int j0n) {
        #pragma unroll
        for (int inst = 0; inst < 2; ++inst) {
            const int row = w*8 + inst*4 + (lane>>4);
            const int grow = j0n + row;
            const int jl = jlist[grow < nact ? grow : 0];
            const unsigned short* src = arr + (size_t)jl*HF + (lane&15)*8;
            __builtin_amdgcn_global_load_lds(
                (const __attribute__((address_space(1))) void*)src,
                (__attribute__((address_space(3))) void*)(rawbase + (w*8 + inst*4)*256),
                16, 0, 0);
        }
    };

    if (nact > 0) {    // prefetch tile 0 into buf 0
        pf(Ap_b, rawA, 0);
        pf(Vp_b, rawV, 0);
    }
    __syncthreads();   // drain: tile-0 raw data landed

    float hacc[4] = {0.f,0.f,0.f,0.f};
    float sae = 0.f;
    float xa0 = 0.f, xa1 = 0.f, xa2 = 0.f;
    const int brow = t >> 4, bcol = (t & 15)*8;   // tile build: row, bf16-col
    const int crow = t >> 3, cg = t & 7;          // c-branch mapping

    for (int tile = 0; tile < ntiles; ++tile) {
        const int j0 = tile*32;
        const int buf = tile & 1;
        char* rA = rawA + buf*8192;
        char* rV = rawV + buf*8192;

        // ---- phase 1: issue next-tile prefetch, then build A tile from raw ----
        pf(Ap_b, rawA + (buf^1)*8192, j0 + 32);
        pf(Vp_b, rawV + (buf^1)*8192, j0 + 32);
        #pragma unroll
        for (int m = 0; m < 2; ++m) {
            const int row = m*16 + brow;
            const int grow = j0 + row;
            const int jl = jlist[grow < nact ? grow : 0];
            const float dsv = ds_all[jl];
            bf16x8 ap = *(const bf16x8*)(rA + row*256 + bcol*2);
            f32x4 al0 = *(const f32x4*)&Al_s[bcol];
            f32x4 al1 = *(const f32x4*)&Al_s[bcol+4];
            f32x4 w0  = *(const f32x4*)&aw1l[bcol];
            f32x4 w1  = *(const f32x4*)&aw1l[bcol+4];
            bf16x8 pk;
            #pragma unroll
            for (int q = 0; q < 4; ++q) {
                pk[q]   = (short)f2bf(silu_f(al0[q] + bf2f(ap[q])   + dsv*w0[q]));
                pk[q+4] = (short)f2bf(silu_f(al1[q] + bf2f(ap[q+4]) + dsv*w1[q]));
            }
            *(bf16x8*)(smem + row*256 + ((bcol*2) ^ ((row & 7) << 4))) = pk;
        }
        __syncthreads();   // bar 1: A ready (also drains prefetch)

        // ---- phase 2: a-GEMM + attn partials; c-branch overlaps ----
        bf16x8 af[4];
        {
            int arow = wj*16 + lr;
            int rb = arow*256, sw = (arow & 7) << 4;
            #pragma unroll
            for (int ks = 0; ks < 4; ++ks)
                af[ks] = *(bf16x8*)(smem + rb + ((lg*16 + ks*64) ^ sw));
        }
        f32x4 acc[4];
        #pragma unroll
        for (int nt = 0; nt < 4; ++nt) {
            acc[nt] = (f32x4){0.f,0.f,0.f,0.f};
            #pragma unroll
            for (int ks = 0; ks < 4; ++ks)
                acc[nt] = __builtin_amdgcn_mfma_f32_16x16x32_bf16(af[ks], wa[nt][ks], acc[nt], 0,0,0);
        }
        // c-branch (VALU; Cp latency hides under MFMA + shfl chain)
        {
            const int growc = j0 + crow;
            const bool okc = growc < nact;
            const int jlc = jlist[okc ? growc : 0];
            const float pmec = okc ? pme[jlc] : 0.f;
            const float dsc = ds_all[jlc];
            float part = 0.f;
            const unsigned short* cp = Cp_b + (size_t)jlc*HF + cg*16;
            #pragma unroll
            for (int u = 0; u < 2; ++u) {
                const int ch = cg*16 + u*8;
                bf16x8 cv = *(const bf16x8*)(cp + u*8);
                f32x4 cl0 = *(const f32x4*)&Cl_s[ch];
                f32x4 cl1 = *(const f32x4*)&Cl_s[ch+4];
                f32x4 w0  = *(const f32x4*)&cw1l[ch];
                f32x4 w1  = *(const f32x4*)&cw1l[ch+4];
                f32x4 s0  = *(const f32x4*)&cW2s[ch];
                f32x4 s1  = *(const f32x4*)&cW2s[ch+4];
                #pragma unroll
                for (int q = 0; q < 4; ++q) {
                    part += silu_f(cl0[q] + bf2f(cv[q])   + dsc*w0[q]) * s0[q];
                    part += silu_f(cl1[q] + bf2f(cv[q+4]) + dsc*w1[q]) * s1[q];
                }
            }
            part += __shfl_xor(part,1); part += __shfl_xor(part,2); part += __shfl_xor(part,4);
            if (cg == 0) {
                float cw = tanh_f(part + cb2v) * pmec;
                xa0 = fmaf(dirx[jlc], cw, xa0);
                xa1 = fmaf(diry[jlc], cw, xa1);
                xa2 = fmaf(dirz[jlc], cw, xa2);
            }
        }
        // attn epilogue partials
        #pragma unroll
        for (int r = 0; r < 4; ++r) {
            float p = 0.f;
            #pragma unroll
            for (int nt = 0; nt < 4; ++nt)
                p += silu_f(acc[nt][r] + ab2v[nt]) * aw3v[nt];
            p += __shfl_xor(p,1); p += __shfl_xor(p,2);
            p += __shfl_xor(p,4); p += __shfl_xor(p,8);
            if (lr == 0) attn_part[wn*32 + wj*16 + lg*4 + r] = p;
        }
        __syncthreads();   // bar 2: attn_part ready

        // ---- phase 3: attn_e (t<32) + build V tile from raw ----
        if (t < 32) {
            const int grow = j0 + t;
            const bool ok = grow < nact;
            const int j = jlist[ok ? grow : 0];
            attn_e[t] = sigmoid_f(attn_part[t] + attn_part[32+t] + ab3v) * (ok ? pme[j] : 0.f);
        }
        #pragma unroll
        for (int m = 0; m < 2; ++m) {
            const int row = m*16 + brow;
            const int grow = j0 + row;
            const int jl = jlist[grow < nact ? grow : 0];
            const float dsv = ds_all[jl];
            bf16x8 vp = *(const bf16x8*)(rV + row*256 + bcol*2);
            f32x4 w0 = *(const f32x4*)&vw1l[bcol];
            f32x4 w1 = *(const f32x4*)&vw1l[bcol+4];
            bf16x8 pk;
            #pragma unroll
            for (int q = 0; q < 4; ++q) {
                pk[q]   = (short)f2bf(silu_f(bf2f(vp[q])   + dsv*w0[q]));
                pk[q+4] = (short)f2bf(silu_f(bf2f(vp[q+4]) + dsv*w1[q]));
            }
            *(bf16x8*)(smem + 8192 + row*256 + ((bcol*2) ^ ((row & 7) << 4))) = pk;
        }
        __syncthreads();   // bar 3: V + attn_e ready

        // ---- phase 4: v-GEMM + h accumulate ----
        bf16x8 vf[4];
        {
            int arow = wj*16 + lr;
            int rb = 8192 + arow*256, sw = (arow & 7) << 4;
            #pragma unroll
            for (int ks = 0; ks < 4; ++ks)
                vf[ks] = *(bf16x8*)(smem + rb + ((lg*16 + ks*64) ^ sw));
        }
        float ae[4];
        #pragma unroll
        for (int r = 0; r < 4; ++r) { ae[r] = attn_e[wj*16 + lg*4 + r]; sae += ae[r]; }
        #pragma unroll
        for (int nt = 0; nt < 4; ++nt) {
            f32x4 a = (f32x4){0.f,0.f,0.f,0.f};
            #pragma unroll
            for (int ks = 0; ks < 4; ++ks)
                a = __builtin_amdgcn_mfma_f32_16x16x32_bf16(vf[ks], wv[nt][ks], a, 0,0,0);
            hacc[nt] += ae[0]*a[0] + ae[1]*a[1] + ae[2]*a[2] + ae[3]*a[3];
        }
    }

    // ---- final reductions (hred aliased over A-tile area; safe: all waves
    // past bar3 of the last tile only touch the V-tile region) ----
    #pragma unroll
    for (int nt = 0; nt < 4; ++nt) {
        hacc[nt] += __shfl_xor(hacc[nt],16);
        hacc[nt] += __shfl_xor(hacc[nt],32);
    }
    sae += __shfl_xor(sae,16);
    sae += __shfl_xor(sae,32);
    if (lg == 0) {
        #pragma unroll
        for (int nt = 0; nt < 4; ++nt)
            hred[wj*128 + wn*64 + nt*16 + lr] = hacc[nt] + vb2v[nt]*sae;
    }
    xa0 += __shfl_xor(xa0,1);  xa1 += __shfl_xor(xa1,1);  xa2 += __shfl_xor(xa2,1);
    xa0 += __shfl_xor(xa0,2);  xa1 += __shfl_xor(xa1,2);  xa2 += __shfl_xor(xa2,2);
    xa0 += __shfl_xor(xa0,4);  xa1 += __shfl_xor(xa1,4);  xa2 += __shfl_xor(xa2,4);
    xa0 += __shfl_xor(xa0,8);  xa1 += __shfl_xor(xa1,8);  xa2 += __shfl_xor(xa2,8);
    xa0 += __shfl_xor(xa0,16); xa1 += __shfl_xor(xa1,16); xa2 += __shfl_xor(xa2,16);
    xa0 += __shfl_xor(xa0,32); xa1 += __shfl_xor(xa1,32); xa2 += __shfl_xor(xa2,32);
    if (lane == 0) { xw[w*3+0]=xa0; xw[w*3+1]=xa1; xw[w*3+2]=xa2; }
    __syncthreads();

    const float lm = ligand_mask[ii];
    if (t < HF) {
        float v = (hred[t] + hred[128+t]) * 0.01f * lm;
        atomicAdd(&out[(size_t)ii*HF + t], v);
    }
    if (t < 3) {
        float v = (xw[t] + xw[3+t] + xw[6+t] + xw[9+t]) * 0.01f * lm;
        atomicAdd(&out[(size_t)NB*NL*HF + ii*3 + t], v);
    }
}

extern "C" void kernel_launch(void* const* d_in, const int* in_sizes, int n_in,
                              void* d_out, int out_size, void* d_ws, size_t ws_size,
                              hipStream_t stream) {
    const float* h_ligand     = (const float*)d_in[0];
    const float* x_ligand     = (const float*)d_in[1];
    const float* h_protein    = (const float*)d_in[2];
    const float* x_protein    = (const float*)d_in[3];
    const float* ligand_mask  = (const float*)d_in[4];
    const float* protein_mask = (const float*)d_in[5];
    const float* aW1 = (const float*)d_in[6];
    const float* ab1 = (const float*)d_in[7];
    const float* aW2 = (const float*)d_in[8];
    const float* ab2 = (const float*)d_in[9];
    const float* aW3 = (const float*)d_in[10];
    const float* ab3 = (const float*)d_in[11];
    const float* vW1 = (const float*)d_in[12];
    const float* vb1 = (const float*)d_in[13];
    const float* vW2 = (const float*)d_in[14];
    const float* vb2 = (const float*)d_in[15];
    const float* cW1 = (const float*)d_in[16];
    const float* cb1 = (const float*)d_in[17];
    const float* cW2 = (const float*)d_in[18];
    const float* cb2 = (const float*)d_in[19];

    float* Al = (float*)d_ws;                              // 512*128 f32
    float* Cl = Al + 512*HF;                               // 512*128 f32
    unsigned short* Ap  = (unsigned short*)(Cl + 512*HF);  // 4096*128 bf16
    unsigned short* Vp  = Ap + (size_t)NB*NP*HF;
    unsigned short* Cp  = Vp + (size_t)NB*NP*HF;
    unsigned short* WaT = Cp + (size_t)NB*NP*HF;           // 128*128 bf16
    unsigned short* WvT = WaT + HF*HF;

    hipMemsetAsync(d_out, 0, (size_t)out_size*sizeof(float), stream);

    precompute_kernel<<<592, 128, 0, stream>>>(
        h_ligand, h_protein, aW1, ab1, vW1, vb1, cW1, cb1, aW2, vW2,
        Al, Cl, Ap, Vp, Cp, WaT, WvT);

    egnn_main_kernel<<<NB*NL*2, 256, 0, stream>>>(
        x_ligand, x_protein, ligand_mask, protein_mask,
        aW1, ab2, aW3, ab3, vW1, vb2, cW1, cW2, cb2,
        Al, Cl, Ap, Vp, Cp, WaT, WvT, (float*)d_out);
}

// Round 13
// 247.592 us; speedup vs baseline: 1.5602x; 1.0160x over previous
//
#include <hip/hip_runtime.h>
#include <hip/hip_bf16.h>
#include <math.h>

#define HF 128
#define NL 128
#define NP 1024
#define NB 4
#define EPSF 1e-8f

typedef short bf16x8 __attribute__((ext_vector_type(8)));
typedef float f32x4 __attribute__((ext_vector_type(4)));

__device__ __forceinline__ float fast_rcp(float x){ return __builtin_amdgcn_rcpf(x); }
__device__ __forceinline__ float silu_f(float x){ return x*fast_rcp(1.f+__expf(-x)); }
__device__ __forceinline__ float sigmoid_f(float x){ return fast_rcp(1.f+__expf(-x)); }
__device__ __forceinline__ float tanh_f(float x){ return 1.f - 2.f*fast_rcp(1.f+__expf(2.f*x)); }
__device__ __forceinline__ unsigned short f2bf(float f){ __hip_bfloat16 h=__float2bfloat16(f); return *(unsigned short*)&h; }
__device__ __forceinline__ float bf2f(short u){ unsigned int x = ((unsigned int)(unsigned short)u)<<16; float r; __builtin_memcpy(&r,&x,4); return r; }
__device__ __forceinline__ unsigned pk2(float a, float b){
    __hip_bfloat162 h = __float22bfloat162_rn(make_float2(a,b));
    return *reinterpret_cast<unsigned*>(&h);
}

// ---------------------------------------------------------------------------
// Precompute (r7's proven version):
//   Al/Cl (f32, ligand), Ap/Vp/Cp (bf16, protein), WaT/WvT transposes.
// ---------------------------------------------------------------------------
__global__ __launch_bounds__(128) void precompute_kernel(
    const float* __restrict__ h_ligand, const float* __restrict__ h_protein,
    const float* __restrict__ aW1, const float* __restrict__ ab1,
    const float* __restrict__ vW1, const float* __restrict__ vb1,
    const float* __restrict__ cW1, const float* __restrict__ cb1,
    const float* __restrict__ aW2, const float* __restrict__ vW2,
    float* __restrict__ Al, float* __restrict__ Cl,
    unsigned short* __restrict__ Ap, unsigned short* __restrict__ Vp,
    unsigned short* __restrict__ Cp,
    unsigned short* __restrict__ WaT, unsigned short* __restrict__ WvT)
{
    const int blk = blockIdx.x, n = threadIdx.x;
    if (blk < 64) {
        __shared__ float rows[8][HF];
        const int r0 = blk*8;
        for (int idx=n; idx<8*HF; idx+=128) rows[idx>>7][idx&127] = h_ligand[r0*HF+idx];
        __syncthreads();
        float aA[8], aC[8];
        const float bA = ab1[n], bC = cb1[n];
        #pragma unroll
        for (int r=0;r<8;++r){ aA[r]=bA; aC[r]=bC; }
        #pragma unroll 4
        for (int k=0;k<HF;++k){
            float wA = aW1[k*HF+n], wC = cW1[k*HF+n];
            #pragma unroll
            for (int r=0;r<8;++r){ aA[r]=fmaf(rows[r][k],wA,aA[r]); aC[r]=fmaf(rows[r][k],wC,aC[r]); }
        }
        #pragma unroll
        for (int r=0;r<8;++r){ Al[(r0+r)*HF+n]=aA[r]; Cl[(r0+r)*HF+n]=aC[r]; }
    } else if (blk < 576) {
        __shared__ float rows[8][HF];
        const int r0 = (blk-64)*8;
        for (int idx=n; idx<8*HF; idx+=128) rows[idx>>7][idx&127] = h_protein[r0*HF+idx];
        __syncthreads();
        float aA[8], aV[8], aC[8];
        const float bV = vb1[n];
        #pragma unroll
        for (int r=0;r<8;++r){ aA[r]=0.f; aV[r]=bV; aC[r]=0.f; }
        #pragma unroll 2
        for (int k=0;k<HF;++k){
            float wA = aW1[(HF+k)*HF+n], wV = vW1[k*HF+n], wC = cW1[(HF+k)*HF+n];
            #pragma unroll
            for (int r=0;r<8;++r){
                float h = rows[r][k];
                aA[r]=fmaf(h,wA,aA[r]); aV[r]=fmaf(h,wV,aV[r]); aC[r]=fmaf(h,wC,aC[r]);
            }
        }
        #pragma unroll
        for (int r=0;r<8;++r){
            Ap[(r0+r)*HF+n]=f2bf(aA[r]); Vp[(r0+r)*HF+n]=f2bf(aV[r]); Cp[(r0+r)*HF+n]=f2bf(aC[r]);
        }
    } else {
        const int m = blk - 576;
        const float* W = (m<8) ? aW2 : vW2;
        unsigned short* WT = (m<8) ? WaT : WvT;
        const int n0 = (m&7)*16;
        #pragma unroll
        for (int kb=0; kb<16; ++kb) {
            int k = kb*8 + (n>>4);
            int col = n0 + (n&15);
            WT[col*HF + k] = f2bf(W[k*HF + col]);
        }
    }
}

// ---------------------------------------------------------------------------
// Main kernel: r7 base (proven 124.8us; 2 blocks/CU reg-capped by 128 AGPR
// resident weights) with per-wave work reduction:
//  - 64-row j-tiles: 3 barriers / 64 rows (was /32)
//  - padded LDS constant arrays: A-build consts 48B stride (2-way, free),
//    c-branch consts 160B stride (conflict-free) [was 4-way conflicted]
//  - packed bf16 converts (__float22bfloat162_rn -> v_cvt_pk_bf16_f32)
//  - 32-bit byte offsets on all gathered row loads (no per-row 64-bit mul)
//  - prefetch removed (r12: neutral -> not latency-bound)
// ---------------------------------------------------------------------------
__global__ __launch_bounds__(256,2) void egnn_main_kernel(
    const float* __restrict__ x_ligand, const float* __restrict__ x_protein,
    const float* __restrict__ ligand_mask, const float* __restrict__ protein_mask,
    const float* __restrict__ aW1, const float* __restrict__ ab2,
    const float* __restrict__ aW3, const float* __restrict__ ab3,
    const float* __restrict__ vW1, const float* __restrict__ vb2,
    const float* __restrict__ cW1, const float* __restrict__ cW2, const float* __restrict__ cb2,
    const float* __restrict__ Al, const float* __restrict__ Cl,
    const unsigned short* __restrict__ Ap, const unsigned short* __restrict__ Vp,
    const unsigned short* __restrict__ Cp,
    const unsigned short* __restrict__ WaT, const unsigned short* __restrict__ WvT,
    float* __restrict__ out)
{
    __shared__ __align__(16) char smem[50432];
    // [0,16384): A tile (64 rows x 256B, swizzled)   [prologue: weight staging 0..32K]
    // [16384,32768): V tile
    float* ds_all = (float*)(smem + 32768);            // [512]
    float* pme    = (float*)(smem + 34816);            // [512]
    float* dirx   = (float*)(smem + 36864);
    float* diry   = (float*)(smem + 38912);
    float* dirz   = (float*)(smem + 40960);
    unsigned short* jlist = (unsigned short*)(smem + 43008); // [512]
    float* AlP    = (float*)(smem + 44032);            // [192] padded: idx = ch + (ch>>3)*4
    float* aw1P   = (float*)(smem + 44800);
    float* vw1P   = (float*)(smem + 45568);
    float* ClP    = (float*)(smem + 46336);            // [160] padded: idx = ch + (ch>>4)*4
    float* cw1P   = (float*)(smem + 46976);
    float* cW2P   = (float*)(smem + 47616);
    float* attn_part = (float*)(smem + 48256);         // [128] = [wn][64]
    float* attn_e = (float*)(smem + 48768);            // [64]
    float* hred   = (float*)(smem + 49024);            // [256]
    float* xw     = (float*)(smem + 50048);            // [12]
    int* nact_p   = (int*)(smem + 50096);

    const int t = threadIdx.x, lane = t&63, w = t>>6;
    const int wj = w>>1, wn = w&1;
    const int lr = lane&15, lg = lane>>4;
    const int bi = blockIdx.x;
    const int half = bi & 1;
    const int ii = bi >> 1;
    const int b = ii >> 7;
    const int jbase = half*512;

    // ---- prologue: geometry + consts; stage WaT ----
    const float xl0 = x_ligand[ii*3+0], xl1 = x_ligand[ii*3+1], xl2 = x_ligand[ii*3+2];
    const float* xp = x_protein + ((size_t)b*NP + jbase)*3;
    const float* pm = protein_mask + (size_t)b*NP + jbase;
    #pragma unroll
    for (int q=0; q<2; ++q) {
        int jj = q*256 + t;
        float r0 = xl0-xp[jj*3+0], r1 = xl1-xp[jj*3+1], r2 = xl2-xp[jj*3+2];
        float ds = r0*r0+r1*r1+r2*r2;
        float dist = sqrtf(ds+EPSF);
        float inv = fast_rcp(dist+EPSF);
        float e = dist < 10.f ? 1.f : 0.f;
        ds_all[jj]=ds; pme[jj]=pm[jj]*e;
        dirx[jj]=r0*inv; diry[jj]=r1*inv; dirz[jj]=r2*inv;
    }
    if (t < HF) {
        const int iA = t + ((t>>3)<<2);
        AlP[iA]  = Al[(size_t)ii*HF+t];
        aw1P[iA] = aW1[256*HF+t];
        vw1P[iA] = vW1[128*HF+t];
        const int iC = t + ((t>>4)<<2);
        ClP[iC]  = Cl[(size_t)ii*HF+t];
        cw1P[iC] = cW1[256*HF+t];
        cW2P[iC] = cW2[t];
    }
    float ab2v[4], aw3v[4], vb2v[4];
    #pragma unroll
    for (int nt=0; nt<4; ++nt) {
        int n = wn*64 + nt*16 + lr;
        ab2v[nt] = ab2[n]; aw3v[nt] = aW3[n]; vb2v[nt] = vb2[n];
    }
    const float ab3v = ab3[0], cb2v = cb2[0];

    for (int c = t; c < 2048; c += 256) {
        int n = c >> 4, kc = c & 15;
        *(bf16x8*)(smem + n*256 + ((kc*16) ^ ((n&7)<<4))) = *(const bf16x8*)(WaT + n*HF + kc*8);
    }
    __syncthreads();   // WaT staged; geometry ready

    if (w == 0) {      // compaction
        int base = 0;
        for (int c=0; c<8; ++c) {
            int jj = c*64 + lane;
            bool act = pme[jj] > 0.f;
            unsigned long long m = __ballot(act);
            int pos = base + __popcll(m & ((1ull<<lane)-1ull));
            if (act) jlist[pos] = (unsigned short)jj;
            base += __popcll(m);
        }
        if (lane == 0) *nact_p = base;
    }
    bf16x8 wa[4][4], wv[4][4];
    #pragma unroll
    for (int nt = 0; nt < 4; ++nt) {
        int ncol = wn*64 + nt*16 + lr;
        int rb = ncol*256, sw = (ncol & 7) << 4;
        #pragma unroll
        for (int ks = 0; ks < 4; ++ks)
            wa[nt][ks] = *(bf16x8*)(smem + rb + ((lg*16 + ks*64) ^ sw));
    }
    __syncthreads();
    for (int c = t; c < 2048; c += 256) {
        int n = c >> 4, kc = c & 15;
        *(bf16x8*)(smem + n*256 + ((kc*16) ^ ((n&7)<<4))) = *(const bf16x8*)(WvT + n*HF + kc*8);
    }
    __syncthreads();
    #pragma unroll
    for (int nt = 0; nt < 4; ++nt) {
        int ncol = wn*64 + nt*16 + lr;
        int rb = ncol*256, sw = (ncol & 7) << 4;
        #pragma unroll
        for (int ks = 0; ks < 4; ++ks)
            wv[nt][ks] = *(bf16x8*)(smem + rb + ((lg*16 + ks*64) ^ sw));
    }
    __syncthreads();   // weights in regs; tile region free; nact visible

    const int nact = *nact_p;
    const int ntiles = (nact + 63) >> 6;

    const char* ApB = (const char*)(Ap + ((size_t)b*NP + jbase)*HF);
    const char* VpB = (const char*)(Vp + ((size_t)b*NP + jbase)*HF);
    const char* CpB = (const char*)(Cp + ((size_t)b*NP + jbase)*HF);

    float hacc[4] = {0.f,0.f,0.f,0.f};
    float sae = 0.f;
    float xa0 = 0.f, xa1 = 0.f, xa2 = 0.f;
    const int brow = t >> 4;                 // tile build: rows m*16+brow
    const int bcol2 = (t & 15)*16;           // byte offset of this thread's 8 bf16
    const int gbA = (t & 15)*12;             // padded const-array word base (48B stride)
    const int crow = t >> 2, cg4 = t & 3;    // c-branch: 64 rows x 4 lanes (32 ch each)

    for (int tile = 0; tile < ntiles; ++tile) {
        const int j0 = tile*64;

        // ---- phase 1: build A tile (64 compacted rows, 4 rows/thread) ----
        #pragma unroll
        for (int m = 0; m < 4; ++m) {
            const int row = m*16 + brow;
            const int grow = j0 + row;
            const int jl = jlist[grow < nact ? grow : 0];
            const float dsv = ds_all[jl];
            bf16x8 ap = *(const bf16x8*)(ApB + jl*256 + bcol2);
            f32x4 al0 = *(const f32x4*)&AlP[gbA];
            f32x4 al1 = *(const f32x4*)&AlP[gbA+4];
            f32x4 w0  = *(const f32x4*)&aw1P[gbA];
            f32x4 w1  = *(const f32x4*)&aw1P[gbA+4];
            float f[8];
            #pragma unroll
            for (int q = 0; q < 4; ++q) {
                f[q]   = silu_f(al0[q] + bf2f(ap[q])   + dsv*w0[q]);
                f[q+4] = silu_f(al1[q] + bf2f(ap[q+4]) + dsv*w1[q]);
            }
            uint4 pk = { pk2(f[0],f[1]), pk2(f[2],f[3]), pk2(f[4],f[5]), pk2(f[6],f[7]) };
            *(uint4*)(smem + row*256 + (bcol2 ^ ((row & 7) << 4))) = pk;
        }
        __syncthreads();   // bar 1: A ready

        // ---- phase 2: a-GEMM (two 32-row blocks) + attn partials + c-branch ----
        #pragma unroll
        for (int rb = 0; rb < 2; ++rb) {
            const int arow = rb*32 + wj*16 + lr;
            bf16x8 af[4];
            {
                int rbase = arow*256, sw = (arow & 7) << 4;
                #pragma unroll
                for (int ks = 0; ks < 4; ++ks)
                    af[ks] = *(bf16x8*)(smem + rbase + ((lg*16 + ks*64) ^ sw));
            }
            f32x4 acc[4];
            #pragma unroll
            for (int nt = 0; nt < 4; ++nt) {
                acc[nt] = (f32x4){0.f,0.f,0.f,0.f};
                #pragma unroll
                for (int ks = 0; ks < 4; ++ks)
                    acc[nt] = __builtin_amdgcn_mfma_f32_16x16x32_bf16(af[ks], wa[nt][ks], acc[nt], 0,0,0);
            }
            #pragma unroll
            for (int r = 0; r < 4; ++r) {
                float p = 0.f;
                #pragma unroll
                for (int nt = 0; nt < 4; ++nt)
                    p += silu_f(acc[nt][r] + ab2v[nt]) * aw3v[nt];
                p += __shfl_xor(p,1); p += __shfl_xor(p,2);
                p += __shfl_xor(p,4); p += __shfl_xor(p,8);
                if (lr == 0) attn_part[wn*64 + rb*32 + wj*16 + lg*4 + r] = p;
            }
        }
        // c-branch (VALU): 64 rows x 4 lanes, 32 channels/lane
        {
            const int growc = j0 + crow;
            const bool okc = growc < nact;
            const int jlc = jlist[okc ? growc : 0];
            const float pmec = okc ? pme[jlc] : 0.f;
            const float dsc = ds_all[jlc];
            float part = 0.f;
            const char* cp = CpB + jlc*256 + cg4*64;
            #pragma unroll
            for (int u = 0; u < 4; ++u) {
                const int ch = cg4*32 + u*8;
                const int gi = ch + ((ch>>4)<<2);
                bf16x8 cv = *(const bf16x8*)(cp + u*16);
                f32x4 cl0 = *(const f32x4*)&ClP[gi];
                f32x4 cl1 = *(const f32x4*)&ClP[gi+4];
                f32x4 w0  = *(const f32x4*)&cw1P[gi];
                f32x4 w1  = *(const f32x4*)&cw1P[gi+4];
                f32x4 s0  = *(const f32x4*)&cW2P[gi];
                f32x4 s1  = *(const f32x4*)&cW2P[gi+4];
                #pragma unroll
                for (int q = 0; q < 4; ++q) {
                    part += silu_f(cl0[q] + bf2f(cv[q])   + dsc*w0[q]) * s0[q];
                    part += silu_f(cl1[q] + bf2f(cv[q+4]) + dsc*w1[q]) * s1[q];
                }
            }
            part += __shfl_xor(part,1); part += __shfl_xor(part,2);
            if (cg4 == 0) {
                float cw = tanh_f(part + cb2v) * pmec;
                xa0 = fmaf(dirx[jlc], cw, xa0);
                xa1 = fmaf(diry[jlc], cw, xa1);
                xa2 = fmaf(dirz[jlc], cw, xa2);
            }
        }
        __syncthreads();   // bar 2: attn_part ready

        // ---- phase 3: attn_e (t<64) + build V tile ----
        if (t < 64) {
            const int grow = j0 + t;
            const bool ok = grow < nact;
            const int j = jlist[ok ? grow : 0];
            attn_e[t] = sigmoid_f(attn_part[t] + attn_part[64+t] + ab3v) * (ok ? pme[j] : 0.f);
        }
        #pragma unroll
        for (int m = 0; m < 4; ++m) {
            const int row = m*16 + brow;
            const int grow = j0 + row;
            const int jl = jlist[grow < nact ? grow : 0];
            const float dsv = ds_all[jl];
            bf16x8 vp = *(const bf16x8*)(VpB + jl*256 + bcol2);
            f32x4 w0 = *(const f32x4*)&vw1P[gbA];
            f32x4 w1 = *(const f32x4*)&vw1P[gbA+4];
            float f[8];
            #pragma unroll
            for (int q = 0; q < 4; ++q) {
                f[q]   = silu_f(bf2f(vp[q])   + dsv*w0[q]);
                f[q+4] = silu_f(bf2f(vp[q+4]) + dsv*w1[q]);
            }
            uint4 pk = { pk2(f[0],f[1]), pk2(f[2],f[3]), pk2(f[4],f[5]), pk2(f[6],f[7]) };
            *(uint4*)(smem + 16384 + row*256 + (bcol2 ^ ((row & 7) << 4))) = pk;
        }
        __syncthreads();   // bar 3: V + attn_e ready

        // ---- phase 4: v-GEMM (two 32-row blocks) + h accumulate ----
        #pragma unroll
        for (int rb = 0; rb < 2; ++rb) {
            const int arow = rb*32 + wj*16 + lr;
            bf16x8 vf[4];
            {
                int rbase = 16384 + arow*256, sw = (arow & 7) << 4;
                #pragma unroll
                for (int ks = 0; ks < 4; ++ks)
                    vf[ks] = *(bf16x8*)(smem + rbase + ((lg*16 + ks*64) ^ sw));
            }
            float ae[4];
            #pragma unroll
            for (int r = 0; r < 4; ++r) { ae[r] = attn_e[rb*32 + wj*16 + lg*4 + r]; sae += ae[r]; }
            #pragma unroll
            for (int nt = 0; nt < 4; ++nt) {
                f32x4 a = (f32x4){0.f,0.f,0.f,0.f};
                #pragma unroll
                for (int ks = 0; ks < 4; ++ks)
                    a = __builtin_amdgcn_mfma_f32_16x16x32_bf16(vf[ks], wv[nt][ks], a, 0,0,0);
                hacc[nt] += ae[0]*a[0] + ae[1]*a[1] + ae[2]*a[2] + ae[3]*a[3];
            }
        }
        __syncthreads();   // tile done (A/V buffers reused next tile)
    }

    // ---- final reductions ----
    #pragma unroll
    for (int nt = 0; nt < 4; ++nt) {
        hacc[nt] += __shfl_xor(hacc[nt],16);
        hacc[nt] += __shfl_xor(hacc[nt],32);
    }
    sae += __shfl_xor(sae,16);
    sae += __shfl_xor(sae,32);
    if (lg == 0) {
        #pragma unroll
        for (int nt = 0; nt < 4; ++nt)
            hred[wj*128 + wn*64 + nt*16 + lr] = hacc[nt] + vb2v[nt]*sae;
    }
    xa0 += __shfl_xor(xa0,1);  xa1 += __shfl_xor(xa1,1);  xa2 += __shfl_xor(xa2,1);
    xa0 += __shfl_xor(xa0,2);  xa1 += __shfl_xor(xa1,2);  xa2 += __shfl_xor(xa2,2);
    xa0 += __shfl_xor(xa0,4);  xa1 += __shfl_xor(xa1,4);  xa2 += __shfl_xor(xa2,4);
    xa0 += __shfl_xor(xa0,8);  xa1 += __shfl_xor(xa1,8);  xa2 += __shfl_xor(xa2,8);
    xa0 += __shfl_xor(xa0,16); xa1 += __shfl_xor(xa1,16); xa2 += __shfl_xor(xa2,16);
    xa0 += __shfl_xor(xa0,32); xa1 += __shfl_xor(xa1,32); xa2 += __shfl_xor(xa2,32);
    if (lane == 0) { xw[w*3+0]=xa0; xw[w*3+1]=xa1; xw[w*3+2]=xa2; }
    __syncthreads();

    const float lm = ligand_mask[ii];
    if (t < HF) {
        float v = (hred[t] + hred[128+t]) * 0.01f * lm;
        atomicAdd(&out[(size_t)ii*HF + t], v);
    }
    if (t < 3) {
        float v = (xw[t] + xw[3+t] + xw[6+t] + xw[9+t]) * 0.01f * lm;
        atomicAdd(&out[(size_t)NB*NL*HF + ii*3 + t], v);
    }
}

extern "C" void kernel_launch(void* const* d_in, const int* in_sizes, int n_in,
                              void* d_out, int out_size, void* d_ws, size_t ws_size,
                              hipStream_t stream) {
    const float* h_ligand     = (const float*)d_in[0];
    const float* x_ligand     = (const float*)d_in[1];
    const float* h_protein    = (const float*)d_in[2];
    const float* x_protein    = (const float*)d_in[3];
    const float* ligand_mask  = (const float*)d_in[4];
    const float* protein_mask = (const float*)d_in[5];
    const float* aW1 = (const float*)d_in[6];
    const float* ab1 = (const float*)d_in[7];
    const float* aW2 = (const float*)d_in[8];
    const float* ab2 = (const float*)d_in[9];
    const float* aW3 = (const float*)d_in[10];
    const float* ab3 = (const float*)d_in[11];
    const float* vW1 = (const float*)d_in[12];
    const float* vb1 = (const float*)d_in[13];
    const float* vW2 = (const float*)d_in[14];
    const float* vb2 = (const float*)d_in[15];
    const float* cW1 = (const float*)d_in[16];
    const float* cb1 = (const float*)d_in[17];
    const float* cW2 = (const float*)d_in[18];
    const float* cb2 = (const float*)d_in[19];

    float* Al = (float*)d_ws;                              // 512*128 f32
    float* Cl = Al + 512*HF;                               // 512*128 f32
    unsigned short* Ap  = (unsigned short*)(Cl + 512*HF);  // 4096*128 bf16
    unsigned short* Vp  = Ap + (size_t)NB*NP*HF;
    unsigned short* Cp  = Vp + (size_t)NB*NP*HF;
    unsigned short* WaT = Cp + (size_t)NB*NP*HF;           // 128*128 bf16
    unsigned short* WvT = WaT + HF*HF;

    hipMemsetAsync(d_out, 0, (size_t)out_size*sizeof(float), stream);

    precompute_kernel<<<592, 128, 0, stream>>>(
        h_ligand, h_protein, aW1, ab1, vW1, vb1, cW1, cb1, aW2, vW2,
        Al, Cl, Ap, Vp, Cp, WaT, WvT);

    egnn_main_kernel<<<NB*NL*2, 256, 0, stream>>>(
        x_ligand, x_protein, ligand_mask, protein_mask,
        aW1, ab2, aW3, ab3, vW1, vb2, cW1, cW2, cb2,
        Al, Cl, Ap, Vp, Cp, WaT, WvT, (float*)d_out);
}